// Round 2
// baseline (6293.239 us; speedup 1.0000x reference)
//
#include <hip/hip_runtime.h>
#include <hip/hip_bf16.h>

// Problem constants
#define BATCH 2
#define SEQ   2048
#define CDIM  768
#define HEADS 12
#define DHEAD 64
#define QKV_N 2304   // 3*CDIM
#define ROWS  4096   // BATCH*SEQ

// ---------------------------------------------------------------------------
// GEMM 1: qkv = x(fp32, MxK) @ qkv_w(fp32, KxN) + qkv_b  -> fp32 ws
// BM=BN=64, BK=16, 256 threads, 4x4 microtile
// ---------------------------------------------------------------------------
__global__ __launch_bounds__(256) void gemm_qkv_kernel(
    const float* __restrict__ A, const float* __restrict__ B,
    const float* __restrict__ bias, float* __restrict__ C,
    int M, int N, int K)
{
    __shared__ float As[16][68];
    __shared__ float Bs[16][68];
    const int tid = threadIdx.x;
    const int tx = tid & 15, ty = tid >> 4;
    const int m_base = blockIdx.y * 64, n_base = blockIdx.x * 64;

    const int arow  = tid >> 2;        // 0..63
    const int akoff = (tid & 3) * 4;   // 0,4,8,12
    const int brow  = tid >> 4;        // 0..15
    const int bcoff = (tid & 15) * 4;  // 0..60

    float acc[4][4] = {};

    for (int k0 = 0; k0 < K; k0 += 16) {
        const float4 av = *reinterpret_cast<const float4*>(
            A + (size_t)(m_base + arow) * K + k0 + akoff);
        As[akoff + 0][arow] = av.x;
        As[akoff + 1][arow] = av.y;
        As[akoff + 2][arow] = av.z;
        As[akoff + 3][arow] = av.w;

        const float4 bv = *reinterpret_cast<const float4*>(
            B + (size_t)(k0 + brow) * N + n_base + bcoff);
        Bs[brow][bcoff + 0] = bv.x;
        Bs[brow][bcoff + 1] = bv.y;
        Bs[brow][bcoff + 2] = bv.z;
        Bs[brow][bcoff + 3] = bv.w;

        __syncthreads();
        #pragma unroll
        for (int k = 0; k < 16; k++) {
            float a[4], b[4];
            #pragma unroll
            for (int i = 0; i < 4; i++) a[i] = As[k][ty * 4 + i];
            #pragma unroll
            for (int j = 0; j < 4; j++) b[j] = Bs[k][tx * 4 + j];
            #pragma unroll
            for (int i = 0; i < 4; i++)
                #pragma unroll
                for (int j = 0; j < 4; j++)
                    acc[i][j] += a[i] * b[j];
        }
        __syncthreads();
    }

    #pragma unroll
    for (int i = 0; i < 4; i++) {
        const int row = m_base + ty * 4 + i;
        #pragma unroll
        for (int j = 0; j < 4; j++) {
            const int col = n_base + tx * 4 + j;
            C[(size_t)row * N + col] = acc[i][j] + bias[col];
        }
    }
}

// ---------------------------------------------------------------------------
// RMSNorm (over Dh=64) + RoPE, in place on q and k slots of qkv (fp32).
// One wave (64 lanes) handles one (b, n, h, s) vector; block = 4 waves.
// ---------------------------------------------------------------------------
__global__ __launch_bounds__(256) void normrope_kernel(
    float* __restrict__ qkv,
    const float* __restrict__ cosb, const float* __restrict__ sinb,
    const float* __restrict__ qn, const float* __restrict__ kn)
{
    const int wid  = blockIdx.x * 4 + (threadIdx.x >> 6);
    const int lane = threadIdx.x & 63;

    const int s  = wid & 1;            // 0 = q, 1 = k
    const int t  = wid >> 1;
    const int h  = t % HEADS;
    const int nb = t / HEADS;          // b*SEQ + n
    const int n  = nb % SEQ;

    float* p = qkv + (size_t)nb * QKV_N + s * CDIM + h * DHEAD;
    float v = p[lane];

    float sq = v * v;
    #pragma unroll
    for (int m = 32; m > 0; m >>= 1) sq += __shfl_xor(sq, m, 64);
    const float rms = rsqrtf(sq * (1.0f / 64.0f) + 1e-6f);

    const float* w = s ? kn : qn;
    const float nv = v * rms * w[lane];

    const float other = __shfl_xor(nv, 1, 64);
    const int i = lane >> 1;
    const float c  = cosb[n * 32 + i];
    const float sn = sinb[n * 32 + i];

    float res;
    if ((lane & 1) == 0) res = nv * c - other * sn;   // even: t0*c - t1*s
    else                 res = other * sn + nv * c;   // odd:  t0*s + t1*c

    p[lane] = res;
}

// ---------------------------------------------------------------------------
// Attention: one block per (query row n, head h, batch b).
// Scores in LDS (2048 fp32), two-pass softmax, coalesced V accumulation.
// Output written back into the q-slot of qkv (safe: each block only reads
// its own q row, which it fully consumed before the write).
// ---------------------------------------------------------------------------
__global__ __launch_bounds__(256) void attn_kernel(float* __restrict__ qkv)
{
    const int n = blockIdx.x;
    const int h = blockIdx.y;
    const int b = blockIdx.z;
    const int tid = threadIdx.x;

    const size_t batch_base = (size_t)b * SEQ * QKV_N;
    const float* q = qkv + batch_base + (size_t)n * QKV_N + h * DHEAD;
    const float* K = qkv + batch_base + CDIM     + h * DHEAD;  // + j*QKV_N
    const float* V = qkv + batch_base + 2 * CDIM + h * DHEAD;  // + j*QKV_N

    __shared__ float s_q[64];
    __shared__ float s_p[SEQ];
    __shared__ float s_red[256];

    if (tid < 64) s_q[tid] = q[tid];
    __syncthreads();

    // Phase 1: scores
    float sc[8];
    float lmax = -INFINITY;
    #pragma unroll
    for (int jj = 0; jj < 8; jj++) {
        const int j = jj * 256 + tid;
        const float* krow = K + (size_t)j * QKV_N;
        float dot = 0.f;
        #pragma unroll
        for (int d = 0; d < 64; d += 4) {
            const float4 kv = *reinterpret_cast<const float4*>(krow + d);
            dot += s_q[d] * kv.x + s_q[d + 1] * kv.y +
                   s_q[d + 2] * kv.z + s_q[d + 3] * kv.w;
        }
        dot *= 0.125f;   // Dh^-0.5
        sc[jj] = dot;
        lmax = fmaxf(lmax, dot);
    }

    // block max
    s_red[tid] = lmax;
    __syncthreads();
    for (int st = 128; st > 0; st >>= 1) {
        if (tid < st) s_red[tid] = fmaxf(s_red[tid], s_red[tid + st]);
        __syncthreads();
    }
    const float m = s_red[0];
    __syncthreads();

    // exp + block sum
    float lsum = 0.f;
    #pragma unroll
    for (int jj = 0; jj < 8; jj++) {
        const float p = expf(sc[jj] - m);
        s_p[jj * 256 + tid] = p;
        lsum += p;
    }
    s_red[tid] = lsum;
    __syncthreads();
    for (int st = 128; st > 0; st >>= 1) {
        if (tid < st) s_red[tid] += s_red[tid + st];
        __syncthreads();
    }
    const float inv_l = 1.0f / s_red[0];
    __syncthreads();

    // Phase 2: out[d] = sum_j p[j] * V[j][d]
    const int grp = tid >> 6, lane = tid & 63;
    float acc = 0.f;
    const float* vcol = V + lane;
    for (int j = grp * 512; j < grp * 512 + 512; j++) {
        acc += s_p[j] * vcol[(size_t)j * QKV_N];
    }
    s_red[tid] = acc;
    __syncthreads();
    if (tid < 64) {
        const float o = (s_red[tid] + s_red[64 + tid] +
                         s_red[128 + tid] + s_red[192 + tid]) * inv_l;
        // write into q slot (this block's own q row, already consumed)
        qkv[batch_base + (size_t)n * QKV_N + h * DHEAD + tid] = o;
    }
}

// ---------------------------------------------------------------------------
// GEMM 2: out = attn_out(fp32, M x K, lda=QKV_N from q-slot) @ proj_w(fp32)
//         + proj_b -> fp32
// ---------------------------------------------------------------------------
__global__ __launch_bounds__(256) void gemm_proj_kernel(
    const float* __restrict__ A, int lda,
    const float* __restrict__ B, const float* __restrict__ bias,
    float* __restrict__ C, int M, int N, int K)
{
    __shared__ float As[16][68];
    __shared__ float Bs[16][68];
    const int tid = threadIdx.x;
    const int tx = tid & 15, ty = tid >> 4;
    const int m_base = blockIdx.y * 64, n_base = blockIdx.x * 64;

    const int arow  = tid >> 2;
    const int akoff = (tid & 3) * 4;
    const int brow  = tid >> 4;
    const int bcoff = (tid & 15) * 4;

    float acc[4][4] = {};

    for (int k0 = 0; k0 < K; k0 += 16) {
        const float4 av = *reinterpret_cast<const float4*>(
            A + (size_t)(m_base + arow) * lda + k0 + akoff);
        As[akoff + 0][arow] = av.x;
        As[akoff + 1][arow] = av.y;
        As[akoff + 2][arow] = av.z;
        As[akoff + 3][arow] = av.w;

        const float4 bv = *reinterpret_cast<const float4*>(
            B + (size_t)(k0 + brow) * N + n_base + bcoff);
        Bs[brow][bcoff + 0] = bv.x;
        Bs[brow][bcoff + 1] = bv.y;
        Bs[brow][bcoff + 2] = bv.z;
        Bs[brow][bcoff + 3] = bv.w;

        __syncthreads();
        #pragma unroll
        for (int k = 0; k < 16; k++) {
            float a[4], b[4];
            #pragma unroll
            for (int i = 0; i < 4; i++) a[i] = As[k][ty * 4 + i];
            #pragma unroll
            for (int j = 0; j < 4; j++) b[j] = Bs[k][tx * 4 + j];
            #pragma unroll
            for (int i = 0; i < 4; i++)
                #pragma unroll
                for (int j = 0; j < 4; j++)
                    acc[i][j] += a[i] * b[j];
        }
        __syncthreads();
    }

    #pragma unroll
    for (int i = 0; i < 4; i++) {
        const int row = m_base + ty * 4 + i;
        #pragma unroll
        for (int j = 0; j < 4; j++) {
            const int col = n_base + tx * 4 + j;
            C[(size_t)row * N + col] = acc[i][j] + bias[col];
        }
    }
}

// ---------------------------------------------------------------------------
extern "C" void kernel_launch(void* const* d_in, const int* in_sizes, int n_in,
                              void* d_out, int out_size, void* d_ws, size_t ws_size,
                              hipStream_t stream)
{
    const float* x      = (const float*)d_in[0];
    const float* cosb   = (const float*)d_in[1];
    const float* sinb   = (const float*)d_in[2];
    const float* qkv_w  = (const float*)d_in[3];
    const float* qkv_b  = (const float*)d_in[4];
    const float* proj_w = (const float*)d_in[5];
    const float* proj_b = (const float*)d_in[6];
    const float* qn_w   = (const float*)d_in[7];
    const float* kn_w   = (const float*)d_in[8];
    float* out = (float*)d_out;

    float* qkv = (float*)d_ws;   // ROWS x QKV_N fp32 = 37.75 MB

    // 1. QKV projection
    gemm_qkv_kernel<<<dim3(QKV_N / 64, ROWS / 64), 256, 0, stream>>>(
        x, qkv_w, qkv_b, qkv, ROWS, QKV_N, CDIM);

    // 2. RMSNorm + RoPE on q,k (in place)
    normrope_kernel<<<(BATCH * SEQ * HEADS * 2) / 4, 256, 0, stream>>>(
        qkv, cosb, sinb, qn_w, kn_w);

    // 3. Attention (out -> q slot of qkv)
    attn_kernel<<<dim3(SEQ, HEADS, BATCH), 256, 0, stream>>>(qkv);

    // 4. Output projection
    gemm_proj_kernel<<<dim3(CDIM / 64, ROWS / 64), 256, 0, stream>>>(
        qkv, QKV_N, proj_w, proj_b, out, ROWS, CDIM, CDIM);
}

// Round 3
// 485.608 us; speedup vs baseline: 12.9595x; 12.9595x over previous
//
#include <hip/hip_runtime.h>
#include <hip/hip_bf16.h>

// Problem constants
#define BATCH 2
#define SEQ   2048
#define CDIM  768
#define HEADS 12
#define DHEAD 64
#define QKV_N 2304   // 3*CDIM
#define ROWS  4096   // BATCH*SEQ

typedef __attribute__((ext_vector_type(4))) float f32x4;
typedef __attribute__((ext_vector_type(8))) short bf16x8;

// fp32 -> bf16 (RNE) bit pattern
__device__ __forceinline__ unsigned short f2b(float f) {
    union { float f; unsigned u; } v; v.f = f;
    unsigned r = v.u + 0x7FFF + ((v.u >> 16) & 1u);
    return (unsigned short)(r >> 16);
}

// ---------------------------------------------------------------------------
// GEMM 1: qkv = x(fp32, MxK) @ qkv_w(fp32, KxN) + qkv_b  -> fp32 ws
// ---------------------------------------------------------------------------
__global__ __launch_bounds__(256) void gemm_qkv_kernel(
    const float* __restrict__ A, const float* __restrict__ B,
    const float* __restrict__ bias, float* __restrict__ C,
    int M, int N, int K)
{
    __shared__ float As[16][68];
    __shared__ float Bs[16][68];
    const int tid = threadIdx.x;
    const int tx = tid & 15, ty = tid >> 4;
    const int m_base = blockIdx.y * 64, n_base = blockIdx.x * 64;

    const int arow  = tid >> 2;
    const int akoff = (tid & 3) * 4;
    const int brow  = tid >> 4;
    const int bcoff = (tid & 15) * 4;

    float acc[4][4] = {};

    for (int k0 = 0; k0 < K; k0 += 16) {
        const float4 av = *reinterpret_cast<const float4*>(
            A + (size_t)(m_base + arow) * K + k0 + akoff);
        As[akoff + 0][arow] = av.x;
        As[akoff + 1][arow] = av.y;
        As[akoff + 2][arow] = av.z;
        As[akoff + 3][arow] = av.w;

        const float4 bv = *reinterpret_cast<const float4*>(
            B + (size_t)(k0 + brow) * N + n_base + bcoff);
        Bs[brow][bcoff + 0] = bv.x;
        Bs[brow][bcoff + 1] = bv.y;
        Bs[brow][bcoff + 2] = bv.z;
        Bs[brow][bcoff + 3] = bv.w;

        __syncthreads();
        #pragma unroll
        for (int k = 0; k < 16; k++) {
            float a[4], b[4];
            #pragma unroll
            for (int i = 0; i < 4; i++) a[i] = As[k][ty * 4 + i];
            #pragma unroll
            for (int j = 0; j < 4; j++) b[j] = Bs[k][tx * 4 + j];
            #pragma unroll
            for (int i = 0; i < 4; i++)
                #pragma unroll
                for (int j = 0; j < 4; j++)
                    acc[i][j] += a[i] * b[j];
        }
        __syncthreads();
    }

    #pragma unroll
    for (int i = 0; i < 4; i++) {
        const int row = m_base + ty * 4 + i;
        #pragma unroll
        for (int j = 0; j < 4; j++) {
            const int col = n_base + tx * 4 + j;
            C[(size_t)row * N + col] = acc[i][j] + bias[col];
        }
    }
}

// ---------------------------------------------------------------------------
// RMSNorm + RoPE, in place on q and k slots of qkv (fp32).
// ---------------------------------------------------------------------------
__global__ __launch_bounds__(256) void normrope_kernel(
    float* __restrict__ qkv,
    const float* __restrict__ cosb, const float* __restrict__ sinb,
    const float* __restrict__ qn, const float* __restrict__ kn)
{
    const int wid  = blockIdx.x * 4 + (threadIdx.x >> 6);
    const int lane = threadIdx.x & 63;

    const int s  = wid & 1;            // 0 = q, 1 = k
    const int t  = wid >> 1;
    const int h  = t % HEADS;
    const int nb = t / HEADS;          // b*SEQ + n
    const int n  = nb % SEQ;

    float* p = qkv + (size_t)nb * QKV_N + s * CDIM + h * DHEAD;
    float v = p[lane];

    float sq = v * v;
    #pragma unroll
    for (int m = 32; m > 0; m >>= 1) sq += __shfl_xor(sq, m, 64);
    const float rms = rsqrtf(sq * (1.0f / 64.0f) + 1e-6f);

    const float* w = s ? kn : qn;
    const float nv = v * rms * w[lane];

    const float other = __shfl_xor(nv, 1, 64);
    const int i = lane >> 1;
    const float c  = cosb[n * 32 + i];
    const float sn = sinb[n * 32 + i];

    float res;
    if ((lane & 1) == 0) res = nv * c - other * sn;
    else                 res = other * sn + nv * c;

    p[lane] = res;
}

// ---------------------------------------------------------------------------
// Flash-style MFMA attention.
// Block = (q-tile of 64, head, batch); 4 waves; wave w owns q rows 16w..16w+15.
// K/V tiles (64 keys) staged in LDS as bf16 (V transposed to [d][k]).
// S = Q K^T via mfma_f32_16x16x32_bf16; online softmax in registers
// (C-layout rows live in the computing lanes); P -> LDS (bf16, A-layout
// round-trip, wave-private); PV via MFMA into fp32 accumulators.
// Output written to the q-slot of qkv.
// ---------------------------------------------------------------------------
#define LPAD 72   // bf16 elements per LDS row (64 + 8 pad, keeps 16B align)

__global__ __launch_bounds__(256) void attn_mfma_kernel(float* __restrict__ qkv)
{
    const int qt = blockIdx.x;   // 0..31
    const int h  = blockIdx.y;
    const int b  = blockIdx.z;
    const int tid  = threadIdx.x;
    const int wave = tid >> 6;
    const int lane = tid & 63;
    const int l16  = lane & 15;
    const int quad = lane >> 4;

    const size_t bb = (size_t)b * SEQ * QKV_N;
    const float* Kg = qkv + bb + CDIM   + h * DHEAD;
    const float* Vg = qkv + bb + 2*CDIM + h * DHEAD;
    float*       Qg = qkv + bb + (size_t)(qt * 64) * QKV_N + h * DHEAD;

    __shared__ unsigned short sK [64 * LPAD];  // [k][d]
    __shared__ unsigned short sVt[64 * LPAD];  // [d][k]
    __shared__ unsigned short sP [64 * LPAD];  // [q][k], wave-private rows

    // Q fragments (A-layout): rows 16*wave + l16, k = 32c + quad*8 + j
    bf16x8 qf[2];
    {
        const float* qrow = Qg + (size_t)(wave * 16 + l16) * QKV_N;
        #pragma unroll
        for (int c = 0; c < 2; c++)
            #pragma unroll
            for (int j = 0; j < 8; j++)
                qf[c][j] = (short)f2b(qrow[c * 32 + quad * 8 + j]);
    }

    f32x4 O[4] = {};                 // 4 d-tiles, C-layout
    float m_run[4], l_run[4];
    #pragma unroll
    for (int r = 0; r < 4; r++) { m_run[r] = -INFINITY; l_run[r] = 0.f; }

    for (int t = 0; t < SEQ / 64; t++) {
        __syncthreads();   // prev iter's LDS reads complete
        // ---- stage K (row-major) and V (transposed) as bf16 ----
        #pragma unroll
        for (int i = 0; i < 4; i++) {
            const int f  = tid + i * 256;    // 0..1023
            const int k  = f >> 4;           // 0..63
            const int d4 = (f & 15) * 4;
            const float4 kv = *reinterpret_cast<const float4*>(
                Kg + (size_t)(t * 64 + k) * QKV_N + d4);
            ushort4 kb;
            kb.x = f2b(kv.x); kb.y = f2b(kv.y);
            kb.z = f2b(kv.z); kb.w = f2b(kv.w);
            *reinterpret_cast<ushort4*>(&sK[k * LPAD + d4]) = kb;

            const float4 vv = *reinterpret_cast<const float4*>(
                Vg + (size_t)(t * 64 + k) * QKV_N + d4);
            sVt[(d4 + 0) * LPAD + k] = f2b(vv.x);
            sVt[(d4 + 1) * LPAD + k] = f2b(vv.y);
            sVt[(d4 + 2) * LPAD + k] = f2b(vv.z);
            sVt[(d4 + 3) * LPAD + k] = f2b(vv.w);
        }
        __syncthreads();

        // ---- S = Q K^T  (4 col-tiles of 16, chained over d) ----
        f32x4 s[4];
        #pragma unroll
        for (int kt = 0; kt < 4; kt++) {
            bf16x8 kf0 = *reinterpret_cast<const bf16x8*>(
                &sK[(kt * 16 + l16) * LPAD + quad * 8]);
            bf16x8 kf1 = *reinterpret_cast<const bf16x8*>(
                &sK[(kt * 16 + l16) * LPAD + 32 + quad * 8]);
            f32x4 acc = {};
            acc = __builtin_amdgcn_mfma_f32_16x16x32_bf16(qf[0], kf0, acc, 0, 0, 0);
            acc = __builtin_amdgcn_mfma_f32_16x16x32_bf16(qf[1], kf1, acc, 0, 0, 0);
            s[kt] = acc;
        }

        // ---- online softmax (row r of this lane = quad*4 + r) ----
        #pragma unroll
        for (int r = 0; r < 4; r++) {
            float smax = -INFINITY;
            #pragma unroll
            for (int kt = 0; kt < 4; kt++) {
                s[kt][r] *= 0.125f;           // Dh^-0.5
                smax = fmaxf(smax, s[kt][r]);
            }
            #pragma unroll
            for (int off = 1; off < 16; off <<= 1)
                smax = fmaxf(smax, __shfl_xor(smax, off, 64));
            const float mn    = fmaxf(m_run[r], smax);
            const float alpha = __expf(m_run[r] - mn);
            float lsum = 0.f;
            #pragma unroll
            for (int kt = 0; kt < 4; kt++) {
                const float p = __expf(s[kt][r] - mn);
                s[kt][r] = p;
                lsum += p;
            }
            #pragma unroll
            for (int off = 1; off < 16; off <<= 1)
                lsum += __shfl_xor(lsum, off, 64);
            l_run[r] = l_run[r] * alpha + lsum;
            m_run[r] = mn;
            #pragma unroll
            for (int dt = 0; dt < 4; dt++) O[dt][r] *= alpha;
            // write P row (C-layout -> LDS); rows are wave-private
            #pragma unroll
            for (int kt = 0; kt < 4; kt++)
                sP[(wave * 16 + quad * 4 + r) * LPAD + kt * 16 + l16] =
                    f2b(s[kt][r]);
        }
        // no barrier: sP rows are written and read only by this wave
        // (in-wave LDS write->read ordering is handled by lgkmcnt)

        // ---- O += P V ----
        bf16x8 pf0 = *reinterpret_cast<const bf16x8*>(
            &sP[(wave * 16 + l16) * LPAD + quad * 8]);
        bf16x8 pf1 = *reinterpret_cast<const bf16x8*>(
            &sP[(wave * 16 + l16) * LPAD + 32 + quad * 8]);
        #pragma unroll
        for (int dt = 0; dt < 4; dt++) {
            bf16x8 vf0 = *reinterpret_cast<const bf16x8*>(
                &sVt[(dt * 16 + l16) * LPAD + quad * 8]);
            bf16x8 vf1 = *reinterpret_cast<const bf16x8*>(
                &sVt[(dt * 16 + l16) * LPAD + 32 + quad * 8]);
            O[dt] = __builtin_amdgcn_mfma_f32_16x16x32_bf16(pf0, vf0, O[dt], 0, 0, 0);
            O[dt] = __builtin_amdgcn_mfma_f32_16x16x32_bf16(pf1, vf1, O[dt], 0, 0, 0);
        }
    }

    // ---- epilogue: O /= l, write to q slot ----
    #pragma unroll
    for (int r = 0; r < 4; r++) {
        const float inv = 1.0f / l_run[r];
        const int row = qt * 64 + wave * 16 + quad * 4 + r;
        float* orow = qkv + bb + (size_t)row * QKV_N + h * DHEAD;
        #pragma unroll
        for (int dt = 0; dt < 4; dt++)
            orow[dt * 16 + l16] = O[dt][r] * inv;
    }
}

// ---------------------------------------------------------------------------
// GEMM 2: out = attn_out(fp32, M x K, lda=QKV_N from q-slot) @ proj_w(fp32)
//         + proj_b -> fp32
// ---------------------------------------------------------------------------
__global__ __launch_bounds__(256) void gemm_proj_kernel(
    const float* __restrict__ A, int lda,
    const float* __restrict__ B, const float* __restrict__ bias,
    float* __restrict__ C, int M, int N, int K)
{
    __shared__ float As[16][68];
    __shared__ float Bs[16][68];
    const int tid = threadIdx.x;
    const int tx = tid & 15, ty = tid >> 4;
    const int m_base = blockIdx.y * 64, n_base = blockIdx.x * 64;

    const int arow  = tid >> 2;
    const int akoff = (tid & 3) * 4;
    const int brow  = tid >> 4;
    const int bcoff = (tid & 15) * 4;

    float acc[4][4] = {};

    for (int k0 = 0; k0 < K; k0 += 16) {
        const float4 av = *reinterpret_cast<const float4*>(
            A + (size_t)(m_base + arow) * lda + k0 + akoff);
        As[akoff + 0][arow] = av.x;
        As[akoff + 1][arow] = av.y;
        As[akoff + 2][arow] = av.z;
        As[akoff + 3][arow] = av.w;

        const float4 bv = *reinterpret_cast<const float4*>(
            B + (size_t)(k0 + brow) * N + n_base + bcoff);
        Bs[brow][bcoff + 0] = bv.x;
        Bs[brow][bcoff + 1] = bv.y;
        Bs[brow][bcoff + 2] = bv.z;
        Bs[brow][bcoff + 3] = bv.w;

        __syncthreads();
        #pragma unroll
        for (int k = 0; k < 16; k++) {
            float a[4], b[4];
            #pragma unroll
            for (int i = 0; i < 4; i++) a[i] = As[k][ty * 4 + i];
            #pragma unroll
            for (int j = 0; j < 4; j++) b[j] = Bs[k][tx * 4 + j];
            #pragma unroll
            for (int i = 0; i < 4; i++)
                #pragma unroll
                for (int j = 0; j < 4; j++)
                    acc[i][j] += a[i] * b[j];
        }
        __syncthreads();
    }

    #pragma unroll
    for (int i = 0; i < 4; i++) {
        const int row = m_base + ty * 4 + i;
        #pragma unroll
        for (int j = 0; j < 4; j++) {
            const int col = n_base + tx * 4 + j;
            C[(size_t)row * N + col] = acc[i][j] + bias[col];
        }
    }
}

// ---------------------------------------------------------------------------
extern "C" void kernel_launch(void* const* d_in, const int* in_sizes, int n_in,
                              void* d_out, int out_size, void* d_ws, size_t ws_size,
                              hipStream_t stream)
{
    const float* x      = (const float*)d_in[0];
    const float* cosb   = (const float*)d_in[1];
    const float* sinb   = (const float*)d_in[2];
    const float* qkv_w  = (const float*)d_in[3];
    const float* qkv_b  = (const float*)d_in[4];
    const float* proj_w = (const float*)d_in[5];
    const float* proj_b = (const float*)d_in[6];
    const float* qn_w   = (const float*)d_in[7];
    const float* kn_w   = (const float*)d_in[8];
    float* out = (float*)d_out;

    float* qkv = (float*)d_ws;   // ROWS x QKV_N fp32 = 37.75 MB

    // 1. QKV projection
    gemm_qkv_kernel<<<dim3(QKV_N / 64, ROWS / 64), 256, 0, stream>>>(
        x, qkv_w, qkv_b, qkv, ROWS, QKV_N, CDIM);

    // 2. RMSNorm + RoPE on q,k (in place)
    normrope_kernel<<<(BATCH * SEQ * HEADS * 2) / 4, 256, 0, stream>>>(
        qkv, cosb, sinb, qn_w, kn_w);

    // 3. Flash MFMA attention (out -> q slot of qkv)
    attn_mfma_kernel<<<dim3(SEQ / 64, HEADS, BATCH), 256, 0, stream>>>(qkv);

    // 4. Output projection
    gemm_proj_kernel<<<dim3(CDIM / 64, ROWS / 64), 256, 0, stream>>>(
        qkv, QKV_N, proj_w, proj_b, out, ROWS, CDIM, CDIM);
}

// Round 5
// 245.515 us; speedup vs baseline: 25.6328x; 1.9779x over previous
//
#include <hip/hip_runtime.h>
#include <hip/hip_bf16.h>

// Problem constants
#define BATCH 2
#define SEQ   2048
#define CDIM  768
#define HEADS 12
#define DHEAD 64
#define QKV_N 2304   // 3*CDIM
#define ROWS  4096   // BATCH*SEQ

typedef unsigned short u16;
typedef unsigned int   u32;
typedef __attribute__((ext_vector_type(4))) float f32x4;
typedef __attribute__((ext_vector_type(8))) short bf16x8;

// fp32 -> bf16 (RNE) bit pattern
__device__ __forceinline__ u16 f2b(float f) {
    union { float f; unsigned u; } v; v.f = f;
    unsigned r = v.u + 0x7FFF + ((v.u >> 16) & 1u);
    return (u16)(r >> 16);
}
// bf16 bits -> fp32
__device__ __forceinline__ float b2f(u16 u) {
    union { unsigned i; float f; } x;
    x.i = ((unsigned)u) << 16;
    return x.f;
}

// async global->LDS 16B copy (per-lane global addr; LDS dest = wave base + lane*16)
__device__ __forceinline__ void load_lds16(const void* g, void* l) {
    __builtin_amdgcn_global_load_lds(
        (const __attribute__((address_space(1))) u32*)g,
        (__attribute__((address_space(3))) u32*)l, 16, 0, 0);
}

// ---------------------------------------------------------------------------
// Convert fp32 -> bf16 (flat, float4 granularity)
// ---------------------------------------------------------------------------
__global__ __launch_bounds__(256) void conv_bf16_kernel(
    const float* __restrict__ in, u16* __restrict__ out)
{
    const int i = blockIdx.x * 256 + threadIdx.x;   // one float4
    const float4 v = reinterpret_cast<const float4*>(in)[i];
    ushort4 o;
    o.x = f2b(v.x); o.y = f2b(v.y); o.z = f2b(v.z); o.w = f2b(v.w);
    reinterpret_cast<ushort4*>(out)[i] = o;
}

// ---------------------------------------------------------------------------
// Transpose-convert: in (R x C fp32, row-major) -> out (C x R bf16, row-major)
// 32x32 tiles, 256 threads.
// ---------------------------------------------------------------------------
__global__ __launch_bounds__(256) void tconv_kernel(
    const float* __restrict__ in, u16* __restrict__ out, int R, int C)
{
    __shared__ float t[32][33];
    const int bi = blockIdx.y, bj = blockIdx.x;
    const int c = threadIdx.x & 31, r0 = threadIdx.x >> 5;
    #pragma unroll
    for (int i = 0; i < 4; i++) {
        const int r = r0 + i * 8;
        t[r][c] = in[(size_t)(bi * 32 + r) * C + bj * 32 + c];
    }
    __syncthreads();
    #pragma unroll
    for (int i = 0; i < 4; i++) {
        const int r = r0 + i * 8;
        out[(size_t)(bj * 32 + r) * R + bi * 32 + c] = f2b(t[c][r]);
    }
}

// ---------------------------------------------------------------------------
// bf16 MFMA GEMM, 128x128 tile, BK=32, 4 waves (2x2), bf16 output + bias.
// A: M x K bf16 (row-major, lda); BT: N x K bf16 (row-major, ldb=K).
// ---------------------------------------------------------------------------
__global__ __launch_bounds__(256) void gemm_qkv_mfma_kernel(
    const u16* __restrict__ A, int lda,
    const u16* __restrict__ BT,
    const float* __restrict__ bias,
    u16* __restrict__ C, int ldc, int K)
{
    __shared__ u16 sA[128 * 32];
    __shared__ u16 sB[128 * 32];
    const int tid = threadIdx.x;
    const int lane = tid & 63;
    const int wave = tid >> 6;
    const int wy = wave >> 1, wx = wave & 1;
    const int l16 = lane & 15, quad = lane >> 4;
    const int m0 = blockIdx.y * 128, n0 = blockIdx.x * 128;

    f32x4 acc[4][4] = {};

    for (int k0 = 0; k0 < K; k0 += 32) {
        __syncthreads();
        #pragma unroll
        for (int r = 0; r < 2; r++) {
            const int f = tid + r * 256;      // 16B granule id, 0..511
            const int row = f >> 2, g = f & 3;
            load_lds16(A  + (size_t)(m0 + row) * lda + k0 + g * 8, &sA[f * 8]);
            load_lds16(BT + (size_t)(n0 + row) * K   + k0 + g * 8, &sB[f * 8]);
        }
        __syncthreads();

        bf16x8 af[4], bfr[4];
        #pragma unroll
        for (int i = 0; i < 4; i++) {
            af[i]  = *reinterpret_cast<const bf16x8*>(
                &sA[(wy * 64 + i * 16 + l16) * 32 + quad * 8]);
            bfr[i] = *reinterpret_cast<const bf16x8*>(
                &sB[(wx * 64 + i * 16 + l16) * 32 + quad * 8]);
        }
        #pragma unroll
        for (int i = 0; i < 4; i++)
            #pragma unroll
            for (int j = 0; j < 4; j++)
                acc[i][j] = __builtin_amdgcn_mfma_f32_16x16x32_bf16(
                    af[i], bfr[j], acc[i][j], 0, 0, 0);
    }

    float bv[4];
    #pragma unroll
    for (int j = 0; j < 4; j++) bv[j] = bias[n0 + wx * 64 + j * 16 + l16];
    #pragma unroll
    for (int i = 0; i < 4; i++)
        #pragma unroll
        for (int r = 0; r < 4; r++) {
            const int row = m0 + wy * 64 + i * 16 + quad * 4 + r;
            #pragma unroll
            for (int j = 0; j < 4; j++) {
                const int col = n0 + wx * 64 + j * 16 + l16;
                C[(size_t)row * ldc + col] = f2b(acc[i][j][r] + bv[j]);
            }
        }
}

// Same GEMM but fp32 output (final projection).
__global__ __launch_bounds__(256) void gemm_proj_mfma_kernel(
    const u16* __restrict__ A, int lda,
    const u16* __restrict__ BT,
    const float* __restrict__ bias,
    float* __restrict__ C, int ldc, int K)
{
    __shared__ u16 sA[128 * 32];
    __shared__ u16 sB[128 * 32];
    const int tid = threadIdx.x;
    const int lane = tid & 63;
    const int wave = tid >> 6;
    const int wy = wave >> 1, wx = wave & 1;
    const int l16 = lane & 15, quad = lane >> 4;
    const int m0 = blockIdx.y * 128, n0 = blockIdx.x * 128;

    f32x4 acc[4][4] = {};

    for (int k0 = 0; k0 < K; k0 += 32) {
        __syncthreads();
        #pragma unroll
        for (int r = 0; r < 2; r++) {
            const int f = tid + r * 256;
            const int row = f >> 2, g = f & 3;
            load_lds16(A  + (size_t)(m0 + row) * lda + k0 + g * 8, &sA[f * 8]);
            load_lds16(BT + (size_t)(n0 + row) * K   + k0 + g * 8, &sB[f * 8]);
        }
        __syncthreads();

        bf16x8 af[4], bfr[4];
        #pragma unroll
        for (int i = 0; i < 4; i++) {
            af[i]  = *reinterpret_cast<const bf16x8*>(
                &sA[(wy * 64 + i * 16 + l16) * 32 + quad * 8]);
            bfr[i] = *reinterpret_cast<const bf16x8*>(
                &sB[(wx * 64 + i * 16 + l16) * 32 + quad * 8]);
        }
        #pragma unroll
        for (int i = 0; i < 4; i++)
            #pragma unroll
            for (int j = 0; j < 4; j++)
                acc[i][j] = __builtin_amdgcn_mfma_f32_16x16x32_bf16(
                    af[i], bfr[j], acc[i][j], 0, 0, 0);
    }

    float bv[4];
    #pragma unroll
    for (int j = 0; j < 4; j++) bv[j] = bias[n0 + wx * 64 + j * 16 + l16];
    #pragma unroll
    for (int i = 0; i < 4; i++)
        #pragma unroll
        for (int r = 0; r < 4; r++) {
            const int row = m0 + wy * 64 + i * 16 + quad * 4 + r;
            #pragma unroll
            for (int j = 0; j < 4; j++) {
                const int col = n0 + wx * 64 + j * 16 + l16;
                C[(size_t)row * ldc + col] = acc[i][j][r] + bv[j];
            }
        }
}

// ---------------------------------------------------------------------------
// RMSNorm + RoPE on bf16 qkv buffer, in place on q,k slots.
// q additionally pre-scaled by Dh^-0.5 = 0.125 (exact in bf16).
// ---------------------------------------------------------------------------
__global__ __launch_bounds__(256) void normrope_kernel(
    u16* __restrict__ qkvb,
    const float* __restrict__ cosb, const float* __restrict__ sinb,
    const float* __restrict__ qn, const float* __restrict__ kn)
{
    const int wid  = blockIdx.x * 4 + (threadIdx.x >> 6);
    const int lane = threadIdx.x & 63;

    const int s  = wid & 1;            // 0 = q, 1 = k
    const int t  = wid >> 1;
    const int h  = t % HEADS;
    const int nb = t / HEADS;          // b*SEQ + n
    const int n  = nb % SEQ;

    u16* p = qkvb + (size_t)nb * QKV_N + s * CDIM + h * DHEAD;
    const float v = b2f(p[lane]);

    float sq = v * v;
    #pragma unroll
    for (int m = 32; m > 0; m >>= 1) sq += __shfl_xor(sq, m, 64);
    const float rms = rsqrtf(sq * (1.0f / 64.0f) + 1e-6f);

    const float* w = s ? kn : qn;
    const float nv = v * rms * w[lane];

    const float other = __shfl_xor(nv, 1, 64);
    const int i = lane >> 1;
    const float c  = cosb[n * 32 + i];
    const float sn = sinb[n * 32 + i];

    float res;
    if ((lane & 1) == 0) res = nv * c - other * sn;
    else                 res = other * sn + nv * c;

    if (s == 0) res *= 0.125f;   // fold Dh^-0.5 into q (exact power of 2)
    p[lane] = f2b(res);
}

// ---------------------------------------------------------------------------
// Flash MFMA attention, bf16-resident, fixed-max softmax.
// |q_scaled|=1, |k|=8 (RMS-normed) => |s| <= 8, exp safe in fp32 without max.
// l accumulated per-lane, reduced once at the end. Output -> q slot (bf16).
// ---------------------------------------------------------------------------
#define AP 80   // LDS row stride in bf16 elems (160 B)

__global__ __launch_bounds__(256) void attn_mfma_kernel(u16* __restrict__ qkvb)
{
    const int qt = blockIdx.x;   // q tile (64 rows)
    const int h  = blockIdx.y;
    const int b  = blockIdx.z;
    const int tid  = threadIdx.x;
    const int wave = tid >> 6;
    const int lane = tid & 63;
    const int l16  = lane & 15;
    const int quad = lane >> 4;

    const size_t bb = (size_t)b * SEQ * QKV_N;
    const u16* Kg = qkvb + bb + CDIM     + h * DHEAD;
    const u16* Vg = qkvb + bb + 2 * CDIM + h * DHEAD;
    const u16* Qg = qkvb + bb + (size_t)(qt * 64) * QKV_N + h * DHEAD;

    __shared__ u16 sK [64 * AP];  // [k][d]
    __shared__ u16 sVt[64 * AP];  // [d][k]
    __shared__ u16 sP [64 * AP];  // [q][k], wave-private rows

    // Q fragments (A-layout): row = wave*16 + l16, k = 32c + quad*8 + j
    bf16x8 qf[2];
    {
        const u16* qrow = Qg + (size_t)(wave * 16 + l16) * QKV_N;
        qf[0] = *reinterpret_cast<const bf16x8*>(qrow + quad * 8);
        qf[1] = *reinterpret_cast<const bf16x8*>(qrow + 32 + quad * 8);
    }

    f32x4 O[4] = {};
    float l_lane[4] = {0.f, 0.f, 0.f, 0.f};

    for (int t = 0; t < SEQ / 64; t++) {
        __syncthreads();   // prev iter's LDS reads complete
        // stage: 64 keys x 64 dims bf16 = 512 x 16B granules; 2 per thread
        #pragma unroll
        for (int rr = 0; rr < 2; rr++) {
            const int f = tid + rr * 256;     // 0..511
            const int k = f >> 3, g = f & 7;  // key row 0..63, 16B chunk 0..7
            const bf16x8 kv = *reinterpret_cast<const bf16x8*>(
                Kg + (size_t)(t * 64 + k) * QKV_N + g * 8);
            *reinterpret_cast<bf16x8*>(&sK[k * AP + g * 8]) = kv;
            const bf16x8 vv = *reinterpret_cast<const bf16x8*>(
                Vg + (size_t)(t * 64 + k) * QKV_N + g * 8);
            #pragma unroll
            for (int e = 0; e < 8; e++)
                sVt[(g * 8 + e) * AP + k] = (u16)vv[e];
        }
        __syncthreads();

        // S = Qs K^T
        f32x4 s[4];
        #pragma unroll
        for (int kt = 0; kt < 4; kt++) {
            bf16x8 kf0 = *reinterpret_cast<const bf16x8*>(
                &sK[(kt * 16 + l16) * AP + quad * 8]);
            bf16x8 kf1 = *reinterpret_cast<const bf16x8*>(
                &sK[(kt * 16 + l16) * AP + 32 + quad * 8]);
            f32x4 a = {};
            a = __builtin_amdgcn_mfma_f32_16x16x32_bf16(qf[0], kf0, a, 0, 0, 0);
            a = __builtin_amdgcn_mfma_f32_16x16x32_bf16(qf[1], kf1, a, 0, 0, 0);
            s[kt] = a;
        }

        // P = exp(S) (no max subtraction: |s|<=8), accumulate l, P -> LDS
        #pragma unroll
        for (int kt = 0; kt < 4; kt++)
            #pragma unroll
            for (int r = 0; r < 4; r++) {
                const float p = __expf(s[kt][r]);
                l_lane[r] += p;
                sP[(wave * 16 + quad * 4 + r) * AP + kt * 16 + l16] = f2b(p);
            }
        // no barrier: sP rows are wave-private (write->read ordered by lgkmcnt)

        // O += P V
        bf16x8 pf0 = *reinterpret_cast<const bf16x8*>(
            &sP[(wave * 16 + l16) * AP + quad * 8]);
        bf16x8 pf1 = *reinterpret_cast<const bf16x8*>(
            &sP[(wave * 16 + l16) * AP + 32 + quad * 8]);
        #pragma unroll
        for (int dt = 0; dt < 4; dt++) {
            bf16x8 vf0 = *reinterpret_cast<const bf16x8*>(
                &sVt[(dt * 16 + l16) * AP + quad * 8]);
            bf16x8 vf1 = *reinterpret_cast<const bf16x8*>(
                &sVt[(dt * 16 + l16) * AP + 32 + quad * 8]);
            O[dt] = __builtin_amdgcn_mfma_f32_16x16x32_bf16(pf0, vf0, O[dt], 0, 0, 0);
            O[dt] = __builtin_amdgcn_mfma_f32_16x16x32_bf16(pf1, vf1, O[dt], 0, 0, 0);
        }
    }

    // reduce l across l16 lanes, write O/l to q slot
    #pragma unroll
    for (int r = 0; r < 4; r++) {
        float lv = l_lane[r];
        #pragma unroll
        for (int off = 1; off < 16; off <<= 1) lv += __shfl_xor(lv, off, 64);
        const float inv = 1.0f / lv;
        const int row = qt * 64 + wave * 16 + quad * 4 + r;
        u16* orow = qkvb + bb + (size_t)row * QKV_N + h * DHEAD;
        #pragma unroll
        for (int dt = 0; dt < 4; dt++)
            orow[dt * 16 + l16] = f2b(O[dt][r] * inv);
    }
}

// ---------------------------------------------------------------------------
extern "C" void kernel_launch(void* const* d_in, const int* in_sizes, int n_in,
                              void* d_out, int out_size, void* d_ws, size_t ws_size,
                              hipStream_t stream)
{
    const float* x      = (const float*)d_in[0];
    const float* cosb   = (const float*)d_in[1];
    const float* sinb   = (const float*)d_in[2];
    const float* qkv_w  = (const float*)d_in[3];
    const float* qkv_b  = (const float*)d_in[4];
    const float* proj_w = (const float*)d_in[5];
    const float* proj_b = (const float*)d_in[6];
    const float* qn_w   = (const float*)d_in[7];
    const float* kn_w   = (const float*)d_in[8];
    float* out = (float*)d_out;

    char* ws = (char*)d_ws;
    u16* qkvb = (u16*)(ws);                    // 4096 x 2304 bf16 = 18,874,368 B
    u16* xb   = (u16*)(ws + 18874368);         // 4096 x 768  bf16 =  6,291,456 B
    u16* wT   = (u16*)(ws + 25165824);         // 2304 x 768  bf16 =  3,538,944 B
    u16* pwT  = (u16*)(ws + 28704768);         //  768 x 768  bf16 =  1,179,648 B
                                               // total 29,884,416 B

    // 0. dtype conversions / transposes
    conv_bf16_kernel<<<(ROWS * CDIM / 4) / 256, 256, 0, stream>>>(x, xb);
    tconv_kernel<<<dim3(QKV_N / 32, CDIM / 32), 256, 0, stream>>>(qkv_w, wT, CDIM, QKV_N);
    tconv_kernel<<<dim3(CDIM / 32, CDIM / 32), 256, 0, stream>>>(proj_w, pwT, CDIM, CDIM);

    // 1. QKV projection (bf16 MFMA) -> bf16 qkv buffer
    gemm_qkv_mfma_kernel<<<dim3(QKV_N / 128, ROWS / 128), 256, 0, stream>>>(
        xb, CDIM, wT, qkv_b, qkvb, QKV_N, CDIM);

    // 2. RMSNorm + RoPE on q,k (in place, q pre-scaled by 0.125)
    normrope_kernel<<<(BATCH * SEQ * HEADS * 2) / 4, 256, 0, stream>>>(
        qkvb, cosb, sinb, qn_w, kn_w);

    // 3. Flash MFMA attention (out -> q slot of qkvb)
    attn_mfma_kernel<<<dim3(SEQ / 64, HEADS, BATCH), 256, 0, stream>>>(qkvb);

    // 4. Output projection (bf16 MFMA, fp32 out)
    gemm_proj_mfma_kernel<<<dim3(CDIM / 128, ROWS / 128), 256, 0, stream>>>(
        qkvb, QKV_N, pwT, proj_b, out, CDIM, CDIM);
}

// Round 6
// 209.729 us; speedup vs baseline: 30.0066x; 1.1706x over previous
//
#include <hip/hip_runtime.h>
#include <hip/hip_bf16.h>

// Problem constants
#define BATCH 2
#define SEQ   2048
#define CDIM  768
#define HEADS 12
#define DHEAD 64
#define QKV_N 2304   // 3*CDIM
#define ROWS  4096   // BATCH*SEQ

typedef unsigned short u16;
typedef unsigned int   u32;
typedef __attribute__((ext_vector_type(4))) float f32x4;
typedef __attribute__((ext_vector_type(8))) short bf16x8;
typedef __attribute__((ext_vector_type(4))) short bf16x4;

// fp32 -> bf16 (RNE) bit pattern
__device__ __forceinline__ u16 f2b(float f) {
    union { float f; unsigned u; } v; v.f = f;
    unsigned r = v.u + 0x7FFF + ((v.u >> 16) & 1u);
    return (u16)(r >> 16);
}
// bf16 bits -> fp32
__device__ __forceinline__ float b2f(u16 u) {
    union { unsigned i; float f; } x;
    x.i = ((unsigned)u) << 16;
    return x.f;
}

// async global->LDS 16B copy (per-lane global addr; LDS dest = wave base + lane*16)
__device__ __forceinline__ void load_lds16(const void* g, void* l) {
    __builtin_amdgcn_global_load_lds(
        (const __attribute__((address_space(1))) u32*)g,
        (__attribute__((address_space(3))) u32*)l, 16, 0, 0);
}

// ---------------------------------------------------------------------------
// Convert fp32 -> bf16 (flat, float4 granularity)
// ---------------------------------------------------------------------------
__global__ __launch_bounds__(256) void conv_bf16_kernel(
    const float* __restrict__ in, u16* __restrict__ out)
{
    const int i = blockIdx.x * 256 + threadIdx.x;   // one float4
    const float4 v = reinterpret_cast<const float4*>(in)[i];
    ushort4 o;
    o.x = f2b(v.x); o.y = f2b(v.y); o.z = f2b(v.z); o.w = f2b(v.w);
    reinterpret_cast<ushort4*>(out)[i] = o;
}

// ---------------------------------------------------------------------------
// Transpose-convert: in (R x C fp32, row-major) -> out (C x R bf16, row-major)
// ---------------------------------------------------------------------------
__global__ __launch_bounds__(256) void tconv_kernel(
    const float* __restrict__ in, u16* __restrict__ out, int R, int C)
{
    __shared__ float t[32][33];
    const int bi = blockIdx.y, bj = blockIdx.x;
    const int c = threadIdx.x & 31, r0 = threadIdx.x >> 5;
    #pragma unroll
    for (int i = 0; i < 4; i++) {
        const int r = r0 + i * 8;
        t[r][c] = in[(size_t)(bi * 32 + r) * C + bj * 32 + c];
    }
    __syncthreads();
    #pragma unroll
    for (int i = 0; i < 4; i++) {
        const int r = r0 + i * 8;
        out[(size_t)(bj * 32 + r) * R + bi * 32 + c] = f2b(t[c][r]);
    }
}

// ---------------------------------------------------------------------------
// bf16 MFMA GEMM, 128x128 tile, BK=32, 4 waves (2x2), bf16 output + bias.
// ---------------------------------------------------------------------------
__global__ __launch_bounds__(256) void gemm_qkv_mfma_kernel(
    const u16* __restrict__ A, int lda,
    const u16* __restrict__ BT,
    const float* __restrict__ bias,
    u16* __restrict__ C, int ldc, int K)
{
    __shared__ u16 sA[128 * 32];
    __shared__ u16 sB[128 * 32];
    const int tid = threadIdx.x;
    const int lane = tid & 63;
    const int wave = tid >> 6;
    const int wy = wave >> 1, wx = wave & 1;
    const int l16 = lane & 15, quad = lane >> 4;
    const int m0 = blockIdx.y * 128, n0 = blockIdx.x * 128;

    f32x4 acc[4][4] = {};

    for (int k0 = 0; k0 < K; k0 += 32) {
        __syncthreads();
        #pragma unroll
        for (int r = 0; r < 2; r++) {
            const int f = tid + r * 256;      // 16B granule id, 0..511
            const int row = f >> 2, g = f & 3;
            load_lds16(A  + (size_t)(m0 + row) * lda + k0 + g * 8, &sA[f * 8]);
            load_lds16(BT + (size_t)(n0 + row) * K   + k0 + g * 8, &sB[f * 8]);
        }
        __syncthreads();

        bf16x8 af[4], bfr[4];
        #pragma unroll
        for (int i = 0; i < 4; i++) {
            af[i]  = *reinterpret_cast<const bf16x8*>(
                &sA[(wy * 64 + i * 16 + l16) * 32 + quad * 8]);
            bfr[i] = *reinterpret_cast<const bf16x8*>(
                &sB[(wx * 64 + i * 16 + l16) * 32 + quad * 8]);
        }
        #pragma unroll
        for (int i = 0; i < 4; i++)
            #pragma unroll
            for (int j = 0; j < 4; j++)
                acc[i][j] = __builtin_amdgcn_mfma_f32_16x16x32_bf16(
                    af[i], bfr[j], acc[i][j], 0, 0, 0);
    }

    float bv[4];
    #pragma unroll
    for (int j = 0; j < 4; j++) bv[j] = bias[n0 + wx * 64 + j * 16 + l16];
    #pragma unroll
    for (int i = 0; i < 4; i++)
        #pragma unroll
        for (int r = 0; r < 4; r++) {
            const int row = m0 + wy * 64 + i * 16 + quad * 4 + r;
            #pragma unroll
            for (int j = 0; j < 4; j++) {
                const int col = n0 + wx * 64 + j * 16 + l16;
                C[(size_t)row * ldc + col] = f2b(acc[i][j][r] + bv[j]);
            }
        }
}

// Same GEMM but fp32 output (final projection).
__global__ __launch_bounds__(256) void gemm_proj_mfma_kernel(
    const u16* __restrict__ A, int lda,
    const u16* __restrict__ BT,
    const float* __restrict__ bias,
    float* __restrict__ C, int ldc, int K)
{
    __shared__ u16 sA[128 * 32];
    __shared__ u16 sB[128 * 32];
    const int tid = threadIdx.x;
    const int lane = tid & 63;
    const int wave = tid >> 6;
    const int wy = wave >> 1, wx = wave & 1;
    const int l16 = lane & 15, quad = lane >> 4;
    const int m0 = blockIdx.y * 128, n0 = blockIdx.x * 128;

    f32x4 acc[4][4] = {};

    for (int k0 = 0; k0 < K; k0 += 32) {
        __syncthreads();
        #pragma unroll
        for (int r = 0; r < 2; r++) {
            const int f = tid + r * 256;
            const int row = f >> 2, g = f & 3;
            load_lds16(A  + (size_t)(m0 + row) * lda + k0 + g * 8, &sA[f * 8]);
            load_lds16(BT + (size_t)(n0 + row) * K   + k0 + g * 8, &sB[f * 8]);
        }
        __syncthreads();

        bf16x8 af[4], bfr[4];
        #pragma unroll
        for (int i = 0; i < 4; i++) {
            af[i]  = *reinterpret_cast<const bf16x8*>(
                &sA[(wy * 64 + i * 16 + l16) * 32 + quad * 8]);
            bfr[i] = *reinterpret_cast<const bf16x8*>(
                &sB[(wx * 64 + i * 16 + l16) * 32 + quad * 8]);
        }
        #pragma unroll
        for (int i = 0; i < 4; i++)
            #pragma unroll
            for (int j = 0; j < 4; j++)
                acc[i][j] = __builtin_amdgcn_mfma_f32_16x16x32_bf16(
                    af[i], bfr[j], acc[i][j], 0, 0, 0);
    }

    float bv[4];
    #pragma unroll
    for (int j = 0; j < 4; j++) bv[j] = bias[n0 + wx * 64 + j * 16 + l16];
    #pragma unroll
    for (int i = 0; i < 4; i++)
        #pragma unroll
        for (int r = 0; r < 4; r++) {
            const int row = m0 + wy * 64 + i * 16 + quad * 4 + r;
            #pragma unroll
            for (int j = 0; j < 4; j++) {
                const int col = n0 + wx * 64 + j * 16 + l16;
                C[(size_t)row * ldc + col] = acc[i][j][r] + bv[j];
            }
        }
}

// ---------------------------------------------------------------------------
// RMSNorm + RoPE on bf16 qkv buffer, in place on q,k slots.
// q additionally pre-scaled by Dh^-0.5 = 0.125 (exact in bf16).
// ---------------------------------------------------------------------------
__global__ __launch_bounds__(256) void normrope_kernel(
    u16* __restrict__ qkvb,
    const float* __restrict__ cosb, const float* __restrict__ sinb,
    const float* __restrict__ qn, const float* __restrict__ kn)
{
    const int wid  = blockIdx.x * 4 + (threadIdx.x >> 6);
    const int lane = threadIdx.x & 63;

    const int s  = wid & 1;            // 0 = q, 1 = k
    const int t  = wid >> 1;
    const int h  = t % HEADS;
    const int nb = t / HEADS;          // b*SEQ + n
    const int n  = nb % SEQ;

    u16* p = qkvb + (size_t)nb * QKV_N + s * CDIM + h * DHEAD;
    const float v = b2f(p[lane]);

    float sq = v * v;
    #pragma unroll
    for (int m = 32; m > 0; m >>= 1) sq += __shfl_xor(sq, m, 64);
    const float rms = rsqrtf(sq * (1.0f / 64.0f) + 1e-6f);

    const float* w = s ? kn : qn;
    const float nv = v * rms * w[lane];

    const float other = __shfl_xor(nv, 1, 64);
    const int i = lane >> 1;
    const float c  = cosb[n * 32 + i];
    const float sn = sinb[n * 32 + i];

    float res;
    if ((lane & 1) == 0) res = nv * c - other * sn;
    else                 res = other * sn + nv * c;

    if (s == 0) res *= 0.125f;   // fold Dh^-0.5 into q (exact power of 2)
    p[lane] = f2b(res);
}

// ---------------------------------------------------------------------------
// Flash MFMA attention, bf16-resident, fixed-max softmax.
// Conflict-free LDS layouts:
//   sK : [k][d], stride 80 u16 (write b128 + read both bank-uniform)
//   sP : [q][k], stride 68 u16 (34 words: 34*4*quad = 8*quad mod 32 spreads
//        quads -> 2-way u16 writes; reads as 4x ds_read_b64, bank-uniform)
//   sVt: [d][k-pairs] u32, stride 32 words, XOR swizzle pw = kpair ^ 4*g
//        (2-way b32 packed writes, bank-uniform b128 reads)
// Register double-buffer: K/V tile t+1 prefetched into VGPRs during compute.
// ---------------------------------------------------------------------------
#define KP 80   // sK stride (u16)
#define PP 68   // sP stride (u16) = 34 words

__global__ __launch_bounds__(256) void attn_mfma_kernel(u16* __restrict__ qkvb)
{
    const int qt = blockIdx.x;   // q tile (64 rows)
    const int h  = blockIdx.y;
    const int b  = blockIdx.z;
    const int tid  = threadIdx.x;
    const int wave = tid >> 6;
    const int lane = tid & 63;
    const int l16  = lane & 15;
    const int quad = lane >> 4;

    const size_t bb = (size_t)b * SEQ * QKV_N;
    const u16* Kg = qkvb + bb + CDIM     + h * DHEAD;
    const u16* Vg = qkvb + bb + 2 * CDIM + h * DHEAD;
    const u16* Qg = qkvb + bb + (size_t)(qt * 64) * QKV_N + h * DHEAD;

    __shared__ u16 sK[64 * KP];
    __shared__ u16 sP[64 * PP];
    __shared__ u32 sVt32[64 * 32];   // [d][word], word = key>>1, XOR-swizzled

    // staging thread mapping
    const int kq = tid >> 3;      // K rows kq and kq+32 (0..31)
    const int g  = tid & 7;       // 16B granule (d = g*8..g*8+7)
    const int kp = tid >> 3;      // V key pair: rows 2kp, 2kp+1

    // Q fragments (A-layout): row = wave*16 + l16, k = 32c + quad*8 + j
    bf16x8 qf[2];
    {
        const u16* qrow = Qg + (size_t)(wave * 16 + l16) * QKV_N;
        qf[0] = *reinterpret_cast<const bf16x8*>(qrow + quad * 8);
        qf[1] = *reinterpret_cast<const bf16x8*>(qrow + 32 + quad * 8);
    }

    f32x4 O[4] = {};
    float l_lane[4] = {0.f, 0.f, 0.f, 0.f};

    bf16x8 kreg[2], vreg[2];
    {   // preload tile 0
        kreg[0] = *reinterpret_cast<const bf16x8*>(Kg + (size_t)(kq)      * QKV_N + g * 8);
        kreg[1] = *reinterpret_cast<const bf16x8*>(Kg + (size_t)(kq + 32) * QKV_N + g * 8);
        vreg[0] = *reinterpret_cast<const bf16x8*>(Vg + (size_t)(2 * kp)     * QKV_N + g * 8);
        vreg[1] = *reinterpret_cast<const bf16x8*>(Vg + (size_t)(2 * kp + 1) * QKV_N + g * 8);
    }

    for (int t = 0; t < SEQ / 64; t++) {
        __syncthreads();   // prev iter's LDS reads complete
        // ---- write staged regs to LDS ----
        *reinterpret_cast<bf16x8*>(&sK[kq * KP + g * 8])        = kreg[0];
        *reinterpret_cast<bf16x8*>(&sK[(kq + 32) * KP + g * 8]) = kreg[1];
        const int pwv = kp ^ (4 * g);   // XOR-swizzled word index
        #pragma unroll
        for (int e = 0; e < 8; e++) {
            const u32 pack = ((u32)(u16)vreg[0][e]) | (((u32)(u16)vreg[1][e]) << 16);
            sVt32[(g * 8 + e) * 32 + pwv] = pack;
        }
        __syncthreads();

        // ---- prefetch next tile into regs (latency hidden by compute) ----
        if (t + 1 < SEQ / 64) {
            const size_t base = (size_t)(t + 1) * 64;
            kreg[0] = *reinterpret_cast<const bf16x8*>(Kg + (base + kq)      * QKV_N + g * 8);
            kreg[1] = *reinterpret_cast<const bf16x8*>(Kg + (base + kq + 32) * QKV_N + g * 8);
            vreg[0] = *reinterpret_cast<const bf16x8*>(Vg + (base + 2 * kp)     * QKV_N + g * 8);
            vreg[1] = *reinterpret_cast<const bf16x8*>(Vg + (base + 2 * kp + 1) * QKV_N + g * 8);
        }

        // ---- S = Qs K^T ----
        f32x4 s[4];
        #pragma unroll
        for (int kt = 0; kt < 4; kt++) {
            bf16x8 kf0 = *reinterpret_cast<const bf16x8*>(
                &sK[(kt * 16 + l16) * KP + quad * 8]);
            bf16x8 kf1 = *reinterpret_cast<const bf16x8*>(
                &sK[(kt * 16 + l16) * KP + 32 + quad * 8]);
            f32x4 a = {};
            a = __builtin_amdgcn_mfma_f32_16x16x32_bf16(qf[0], kf0, a, 0, 0, 0);
            a = __builtin_amdgcn_mfma_f32_16x16x32_bf16(qf[1], kf1, a, 0, 0, 0);
            s[kt] = a;
        }

        // ---- P = exp(S) (|s|<=8, no max needed), accumulate l, P -> LDS ----
        #pragma unroll
        for (int kt = 0; kt < 4; kt++)
            #pragma unroll
            for (int r = 0; r < 4; r++) {
                const float p = __expf(s[kt][r]);
                l_lane[r] += p;
                sP[(wave * 16 + quad * 4 + r) * PP + kt * 16 + l16] = f2b(p);
            }
        // no barrier: sP rows are wave-private (write->read ordered by lgkmcnt)

        // ---- O += P V ----
        union { bf16x8 v8; bf16x4 v4[2]; } p0u, p1u;
        {
            const int prow = (wave * 16 + l16) * PP;
            p0u.v4[0] = *reinterpret_cast<const bf16x4*>(&sP[prow + quad * 8]);
            p0u.v4[1] = *reinterpret_cast<const bf16x4*>(&sP[prow + quad * 8 + 4]);
            p1u.v4[0] = *reinterpret_cast<const bf16x4*>(&sP[prow + 32 + quad * 8]);
            p1u.v4[1] = *reinterpret_cast<const bf16x4*>(&sP[prow + 32 + quad * 8 + 4]);
        }
        #pragma unroll
        for (int dt = 0; dt < 4; dt++) {
            const int row = dt * 16 + l16;
            const int sw  = 4 * ((row >> 3) & 7);
            bf16x8 vf0 = *reinterpret_cast<const bf16x8*>(
                &sVt32[row * 32 + ((quad * 4) ^ sw)]);
            bf16x8 vf1 = *reinterpret_cast<const bf16x8*>(
                &sVt32[row * 32 + ((16 + quad * 4) ^ sw)]);
            O[dt] = __builtin_amdgcn_mfma_f32_16x16x32_bf16(p0u.v8, vf0, O[dt], 0, 0, 0);
            O[dt] = __builtin_amdgcn_mfma_f32_16x16x32_bf16(p1u.v8, vf1, O[dt], 0, 0, 0);
        }
    }

    // reduce l across l16 lanes, write O/l to q slot
    #pragma unroll
    for (int r = 0; r < 4; r++) {
        float lv = l_lane[r];
        #pragma unroll
        for (int off = 1; off < 16; off <<= 1) lv += __shfl_xor(lv, off, 64);
        const float inv = 1.0f / lv;
        const int row = qt * 64 + wave * 16 + quad * 4 + r;
        u16* orow = qkvb + bb + (size_t)row * QKV_N + h * DHEAD;
        #pragma unroll
        for (int dt = 0; dt < 4; dt++)
            orow[dt * 16 + l16] = f2b(O[dt][r] * inv);
    }
}

// ---------------------------------------------------------------------------
extern "C" void kernel_launch(void* const* d_in, const int* in_sizes, int n_in,
                              void* d_out, int out_size, void* d_ws, size_t ws_size,
                              hipStream_t stream)
{
    const float* x      = (const float*)d_in[0];
    const float* cosb   = (const float*)d_in[1];
    const float* sinb   = (const float*)d_in[2];
    const float* qkv_w  = (const float*)d_in[3];
    const float* qkv_b  = (const float*)d_in[4];
    const float* proj_w = (const float*)d_in[5];
    const float* proj_b = (const float*)d_in[6];
    const float* qn_w   = (const float*)d_in[7];
    const float* kn_w   = (const float*)d_in[8];
    float* out = (float*)d_out;

    char* ws = (char*)d_ws;
    u16* qkvb = (u16*)(ws);                    // 4096 x 2304 bf16 = 18,874,368 B
    u16* xb   = (u16*)(ws + 18874368);         // 4096 x 768  bf16 =  6,291,456 B
    u16* wT   = (u16*)(ws + 25165824);         // 2304 x 768  bf16 =  3,538,944 B
    u16* pwT  = (u16*)(ws + 28704768);         //  768 x 768  bf16 =  1,179,648 B

    // 0. dtype conversions / transposes
    conv_bf16_kernel<<<(ROWS * CDIM / 4) / 256, 256, 0, stream>>>(x, xb);
    tconv_kernel<<<dim3(QKV_N / 32, CDIM / 32), 256, 0, stream>>>(qkv_w, wT, CDIM, QKV_N);
    tconv_kernel<<<dim3(CDIM / 32, CDIM / 32), 256, 0, stream>>>(proj_w, pwT, CDIM, CDIM);

    // 1. QKV projection (bf16 MFMA) -> bf16 qkv buffer
    gemm_qkv_mfma_kernel<<<dim3(QKV_N / 128, ROWS / 128), 256, 0, stream>>>(
        xb, CDIM, wT, qkv_b, qkvb, QKV_N, CDIM);

    // 2. RMSNorm + RoPE on q,k (in place, q pre-scaled by 0.125)
    normrope_kernel<<<(BATCH * SEQ * HEADS * 2) / 4, 256, 0, stream>>>(
        qkvb, cosb, sinb, qn_w, kn_w);

    // 3. Flash MFMA attention (out -> q slot of qkvb)
    attn_mfma_kernel<<<dim3(SEQ / 64, HEADS, BATCH), 256, 0, stream>>>(qkvb);

    // 4. Output projection (bf16 MFMA, fp32 out)
    gemm_proj_mfma_kernel<<<dim3(CDIM / 128, ROWS / 128), 256, 0, stream>>>(
        qkvb, QKV_N, pwT, proj_b, out, CDIM, CDIM);
}

// Round 7
// 199.920 us; speedup vs baseline: 31.4788x; 1.0491x over previous
//
#include <hip/hip_runtime.h>
#include <hip/hip_bf16.h>

// Problem constants
#define BATCH 2
#define SEQ   2048
#define CDIM  768
#define HEADS 12
#define DHEAD 64
#define QKV_N 2304   // 3*CDIM
#define ROWS  4096   // BATCH*SEQ

typedef unsigned short u16;
typedef unsigned int   u32;
typedef __attribute__((ext_vector_type(4))) float f32x4;
typedef __attribute__((ext_vector_type(8))) short bf16x8;
typedef __attribute__((ext_vector_type(4))) short bf16x4;

// fp32 -> bf16 (RNE) bit pattern
__device__ __forceinline__ u16 f2b(float f) {
    union { float f; unsigned u; } v; v.f = f;
    unsigned r = v.u + 0x7FFF + ((v.u >> 16) & 1u);
    return (u16)(r >> 16);
}
// bf16 bits -> fp32
__device__ __forceinline__ float b2f(u16 u) {
    union { unsigned i; float f; } x;
    x.i = ((unsigned)u) << 16;
    return x.f;
}

// async global->LDS 16B copy
__device__ __forceinline__ void load_lds16(const void* g, void* l) {
    __builtin_amdgcn_global_load_lds(
        (const __attribute__((address_space(1))) u32*)g,
        (__attribute__((address_space(3))) u32*)l, 16, 0, 0);
}

// ---------------------------------------------------------------------------
// Fused prep: x->bf16 (blocks [0,3072)), qkv_w transpose-convert
// (blocks [3072,4800)), proj_w transpose-convert (blocks [4800,5376)).
// ---------------------------------------------------------------------------
#define PREP_CONV 3072          // 4096*768/4 float4 / 256
#define PREP_TQ   1728          // (2304/32) x (768/32)
#define PREP_TP   576           // (768/32) x (768/32)

__device__ __forceinline__ void tconv_body(
    const float* __restrict__ in, u16* __restrict__ out, int R, int C,
    int bi, int bj)
{
    __shared__ float t[32][33];
    const int c = threadIdx.x & 31, r0 = threadIdx.x >> 5;
    #pragma unroll
    for (int i = 0; i < 4; i++) {
        const int r = r0 + i * 8;
        t[r][c] = in[(size_t)(bi * 32 + r) * C + bj * 32 + c];
    }
    __syncthreads();
    #pragma unroll
    for (int i = 0; i < 4; i++) {
        const int r = r0 + i * 8;
        out[(size_t)(bj * 32 + r) * R + bi * 32 + c] = f2b(t[c][r]);
    }
}

__global__ __launch_bounds__(256) void prep_kernel(
    const float* __restrict__ x, u16* __restrict__ xb,
    const float* __restrict__ qkv_w, u16* __restrict__ wT,
    const float* __restrict__ proj_w, u16* __restrict__ pwT)
{
    const int bid = blockIdx.x;
    if (bid < PREP_CONV) {
        const int i = bid * 256 + threadIdx.x;
        const float4 v = reinterpret_cast<const float4*>(x)[i];
        ushort4 o;
        o.x = f2b(v.x); o.y = f2b(v.y); o.z = f2b(v.z); o.w = f2b(v.w);
        reinterpret_cast<ushort4*>(xb)[i] = o;
    } else if (bid < PREP_CONV + PREP_TQ) {
        const int t = bid - PREP_CONV;
        tconv_body(qkv_w, wT, CDIM, QKV_N, t / 72, t % 72);
    } else {
        const int t = bid - PREP_CONV - PREP_TQ;
        tconv_body(proj_w, pwT, CDIM, CDIM, t / 24, t % 24);
    }
}

// ---------------------------------------------------------------------------
// bf16 MFMA GEMM 128x128 BK32 + FUSED RMSNorm + RoPE epilogue.
// Each wave's 64-col block = one (s,head) slice; q/k normed+roped in
// registers (RMS: j-reg sum + shfl over l16; RoPE partner = lane^1),
// q pre-scaled by Dh^-0.5. v written straight through.
// ---------------------------------------------------------------------------
__global__ __launch_bounds__(256) void gemm_qkv_mfma_kernel(
    const u16* __restrict__ A, int lda,
    const u16* __restrict__ BT,
    const float* __restrict__ bias,
    const float* __restrict__ cosb, const float* __restrict__ sinb,
    const float* __restrict__ qn, const float* __restrict__ kn,
    u16* __restrict__ C, int ldc, int K)
{
    __shared__ u16 sA[128 * 32];
    __shared__ u16 sB[128 * 32];
    const int tid = threadIdx.x;
    const int lane = tid & 63;
    const int wave = tid >> 6;
    const int wy = wave >> 1, wx = wave & 1;
    const int l16 = lane & 15, quad = lane >> 4;
    const int m0 = blockIdx.y * 128, n0 = blockIdx.x * 128;

    f32x4 acc[4][4] = {};

    for (int k0 = 0; k0 < K; k0 += 32) {
        __syncthreads();
        #pragma unroll
        for (int r = 0; r < 2; r++) {
            const int f = tid + r * 256;      // 16B granule id, 0..511
            const int row = f >> 2, g = f & 3;
            load_lds16(A  + (size_t)(m0 + row) * lda + k0 + g * 8, &sA[f * 8]);
            load_lds16(BT + (size_t)(n0 + row) * K   + k0 + g * 8, &sB[f * 8]);
        }
        __syncthreads();

        bf16x8 af[4], bfr[4];
        #pragma unroll
        for (int i = 0; i < 4; i++) {
            af[i]  = *reinterpret_cast<const bf16x8*>(
                &sA[(wy * 64 + i * 16 + l16) * 32 + quad * 8]);
            bfr[i] = *reinterpret_cast<const bf16x8*>(
                &sB[(wx * 64 + i * 16 + l16) * 32 + quad * 8]);
        }
        #pragma unroll
        for (int i = 0; i < 4; i++)
            #pragma unroll
            for (int j = 0; j < 4; j++)
                acc[i][j] = __builtin_amdgcn_mfma_f32_16x16x32_bf16(
                    af[i], bfr[j], acc[i][j], 0, 0, 0);
    }

    // ---- fused epilogue ----
    const int cb = (n0 + wx * 64) >> 6;   // 64-col block, 0..35
    const int s  = cb / 12;               // 0=q, 1=k, 2=v
    float bv[4];
    #pragma unroll
    for (int j = 0; j < 4; j++) bv[j] = bias[n0 + wx * 64 + j * 16 + l16];
    float wv[4];
    if (s < 2) {
        const float* wn = (s == 0) ? qn : kn;
        #pragma unroll
        for (int j = 0; j < 4; j++) wv[j] = wn[j * 16 + l16];
    }

    #pragma unroll
    for (int i = 0; i < 4; i++) {
        #pragma unroll
        for (int r = 0; r < 4; r++) {
            const int row = m0 + wy * 64 + i * 16 + quad * 4 + r;
            float v[4];
            #pragma unroll
            for (int j = 0; j < 4; j++) v[j] = acc[i][j][r] + bv[j];

            if (s < 2) {
                float sq = v[0]*v[0] + v[1]*v[1] + v[2]*v[2] + v[3]*v[3];
                #pragma unroll
                for (int off = 1; off < 16; off <<= 1)
                    sq += __shfl_xor(sq, off, 64);
                const float rms = rsqrtf(sq * (1.0f / 64.0f) + 1e-6f);
                const int n = row & (SEQ - 1);
                #pragma unroll
                for (int j = 0; j < 4; j++) {
                    const float nv = v[j] * rms * wv[j];
                    const float other = __shfl_xor(nv, 1, 64);
                    const int d = j * 16 + l16;
                    const float c  = cosb[n * 32 + (d >> 1)];
                    const float sn = sinb[n * 32 + (d >> 1)];
                    float res = ((l16 & 1) == 0) ? nv * c - other * sn
                                                 : other * sn + nv * c;
                    if (s == 0) res *= 0.125f;   // fold Dh^-0.5 into q
                    v[j] = res;
                }
            }
            #pragma unroll
            for (int j = 0; j < 4; j++) {
                const int col = n0 + wx * 64 + j * 16 + l16;
                C[(size_t)row * ldc + col] = f2b(v[j]);
            }
        }
    }
}

// ---------------------------------------------------------------------------
// bf16 MFMA GEMM 128x64 BK32, fp32 output + bias (final projection).
// ---------------------------------------------------------------------------
__global__ __launch_bounds__(256) void gemm_proj_mfma_kernel(
    const u16* __restrict__ A, int lda,
    const u16* __restrict__ BT,
    const float* __restrict__ bias,
    float* __restrict__ C, int ldc, int K)
{
    __shared__ u16 sA[128 * 32];
    __shared__ u16 sB[64 * 32];
    const int tid = threadIdx.x;
    const int lane = tid & 63;
    const int wave = tid >> 6;
    const int wy = wave >> 1, wx = wave & 1;
    const int l16 = lane & 15, quad = lane >> 4;
    const int m0 = blockIdx.y * 128, n0 = blockIdx.x * 64;

    f32x4 acc[4][2] = {};

    for (int k0 = 0; k0 < K; k0 += 32) {
        __syncthreads();
        #pragma unroll
        for (int r = 0; r < 2; r++) {
            const int f = tid + r * 256;
            const int row = f >> 2, g = f & 3;
            load_lds16(A + (size_t)(m0 + row) * lda + k0 + g * 8, &sA[f * 8]);
        }
        {
            const int row = tid >> 2, g = tid & 3;
            load_lds16(BT + (size_t)(n0 + row) * K + k0 + g * 8, &sB[tid * 8]);
        }
        __syncthreads();

        bf16x8 af[4], bfr[2];
        #pragma unroll
        for (int i = 0; i < 4; i++)
            af[i] = *reinterpret_cast<const bf16x8*>(
                &sA[(wy * 64 + i * 16 + l16) * 32 + quad * 8]);
        #pragma unroll
        for (int j = 0; j < 2; j++)
            bfr[j] = *reinterpret_cast<const bf16x8*>(
                &sB[(wx * 32 + j * 16 + l16) * 32 + quad * 8]);
        #pragma unroll
        for (int i = 0; i < 4; i++)
            #pragma unroll
            for (int j = 0; j < 2; j++)
                acc[i][j] = __builtin_amdgcn_mfma_f32_16x16x32_bf16(
                    af[i], bfr[j], acc[i][j], 0, 0, 0);
    }

    float bv[2];
    #pragma unroll
    for (int j = 0; j < 2; j++) bv[j] = bias[n0 + wx * 32 + j * 16 + l16];
    #pragma unroll
    for (int i = 0; i < 4; i++)
        #pragma unroll
        for (int r = 0; r < 4; r++) {
            const int row = m0 + wy * 64 + i * 16 + quad * 4 + r;
            #pragma unroll
            for (int j = 0; j < 2; j++) {
                const int col = n0 + wx * 32 + j * 16 + l16;
                C[(size_t)row * ldc + col] = acc[i][j][r] + bv[j];
            }
        }
}

// ---------------------------------------------------------------------------
// Flash MFMA attention, bf16-resident, fixed-max softmax, double-buffered
// K/V LDS (one barrier per tile). Conflict-mitigated layouts (round-6).
// ---------------------------------------------------------------------------
#define KP 80   // sK stride (u16)
#define PP 68   // sP stride (u16) = 34 words

__global__ __launch_bounds__(256) void attn_mfma_kernel(u16* __restrict__ qkvb)
{
    const int qt = blockIdx.x;   // q tile (64 rows)
    const int h  = blockIdx.y;
    const int b  = blockIdx.z;
    const int tid  = threadIdx.x;
    const int wave = tid >> 6;
    const int lane = tid & 63;
    const int l16  = lane & 15;
    const int quad = lane >> 4;

    const size_t bb = (size_t)b * SEQ * QKV_N;
    const u16* Kg = qkvb + bb + CDIM     + h * DHEAD;
    const u16* Vg = qkvb + bb + 2 * CDIM + h * DHEAD;
    const u16* Qg = qkvb + bb + (size_t)(qt * 64) * QKV_N + h * DHEAD;

    __shared__ u16 sK[2][64 * KP];
    __shared__ u32 sVt32[2][64 * 32];
    __shared__ u16 sP[64 * PP];

    // staging thread mapping
    const int kq = tid >> 3;      // K rows kq, kq+32
    const int g  = tid & 7;       // 16B granule (d = g*8..g*8+7)
    const int kp = tid >> 3;      // V key pair: rows 2kp, 2kp+1

    bf16x8 qf[2];
    {
        const u16* qrow = Qg + (size_t)(wave * 16 + l16) * QKV_N;
        qf[0] = *reinterpret_cast<const bf16x8*>(qrow + quad * 8);
        qf[1] = *reinterpret_cast<const bf16x8*>(qrow + 32 + quad * 8);
    }

    f32x4 O[4] = {};
    float l_lane[4] = {0.f, 0.f, 0.f, 0.f};

    bf16x8 kreg[2], vreg[2];
    kreg[0] = *reinterpret_cast<const bf16x8*>(Kg + (size_t)(kq)      * QKV_N + g * 8);
    kreg[1] = *reinterpret_cast<const bf16x8*>(Kg + (size_t)(kq + 32) * QKV_N + g * 8);
    vreg[0] = *reinterpret_cast<const bf16x8*>(Vg + (size_t)(2 * kp)     * QKV_N + g * 8);
    vreg[1] = *reinterpret_cast<const bf16x8*>(Vg + (size_t)(2 * kp + 1) * QKV_N + g * 8);

    for (int t = 0; t < SEQ / 64; t++) {
        const int cur = t & 1;
        // ---- write staged regs to LDS (buffer cur) ----
        *reinterpret_cast<bf16x8*>(&sK[cur][kq * KP + g * 8])        = kreg[0];
        *reinterpret_cast<bf16x8*>(&sK[cur][(kq + 32) * KP + g * 8]) = kreg[1];
        const int pwv = kp ^ (4 * g);
        #pragma unroll
        for (int e = 0; e < 8; e++) {
            const u32 pack = ((u32)(u16)vreg[0][e]) | (((u32)(u16)vreg[1][e]) << 16);
            sVt32[cur][(g * 8 + e) * 32 + pwv] = pack;
        }
        // ---- prefetch next tile into regs ----
        if (t + 1 < SEQ / 64) {
            const size_t base = (size_t)(t + 1) * 64;
            kreg[0] = *reinterpret_cast<const bf16x8*>(Kg + (base + kq)      * QKV_N + g * 8);
            kreg[1] = *reinterpret_cast<const bf16x8*>(Kg + (base + kq + 32) * QKV_N + g * 8);
            vreg[0] = *reinterpret_cast<const bf16x8*>(Vg + (base + 2 * kp)     * QKV_N + g * 8);
            vreg[1] = *reinterpret_cast<const bf16x8*>(Vg + (base + 2 * kp + 1) * QKV_N + g * 8);
        }
        __syncthreads();   // buffer cur fully written; prev buffer reads done

        // ---- S = Qs K^T ----
        f32x4 s[4];
        #pragma unroll
        for (int kt = 0; kt < 4; kt++) {
            bf16x8 kf0 = *reinterpret_cast<const bf16x8*>(
                &sK[cur][(kt * 16 + l16) * KP + quad * 8]);
            bf16x8 kf1 = *reinterpret_cast<const bf16x8*>(
                &sK[cur][(kt * 16 + l16) * KP + 32 + quad * 8]);
            f32x4 a = {};
            a = __builtin_amdgcn_mfma_f32_16x16x32_bf16(qf[0], kf0, a, 0, 0, 0);
            a = __builtin_amdgcn_mfma_f32_16x16x32_bf16(qf[1], kf1, a, 0, 0, 0);
            s[kt] = a;
        }

        // ---- P = exp(S) (|s|<=8), accumulate l, P -> LDS ----
        #pragma unroll
        for (int kt = 0; kt < 4; kt++)
            #pragma unroll
            for (int r = 0; r < 4; r++) {
                const float p = __expf(s[kt][r]);
                l_lane[r] += p;
                sP[(wave * 16 + quad * 4 + r) * PP + kt * 16 + l16] = f2b(p);
            }
        // no barrier: sP rows wave-private (write->read ordered by lgkmcnt)

        // ---- O += P V ----
        union { bf16x8 v8; bf16x4 v4[2]; } p0u, p1u;
        {
            const int prow = (wave * 16 + l16) * PP;
            p0u.v4[0] = *reinterpret_cast<const bf16x4*>(&sP[prow + quad * 8]);
            p0u.v4[1] = *reinterpret_cast<const bf16x4*>(&sP[prow + quad * 8 + 4]);
            p1u.v4[0] = *reinterpret_cast<const bf16x4*>(&sP[prow + 32 + quad * 8]);
            p1u.v4[1] = *reinterpret_cast<const bf16x4*>(&sP[prow + 32 + quad * 8 + 4]);
        }
        #pragma unroll
        for (int dt = 0; dt < 4; dt++) {
            const int row = dt * 16 + l16;
            const int sw  = 4 * ((row >> 3) & 7);
            bf16x8 vf0 = *reinterpret_cast<const bf16x8*>(
                &sVt32[cur][row * 32 + ((quad * 4) ^ sw)]);
            bf16x8 vf1 = *reinterpret_cast<const bf16x8*>(
                &sVt32[cur][row * 32 + ((16 + quad * 4) ^ sw)]);
            O[dt] = __builtin_amdgcn_mfma_f32_16x16x32_bf16(p0u.v8, vf0, O[dt], 0, 0, 0);
            O[dt] = __builtin_amdgcn_mfma_f32_16x16x32_bf16(p1u.v8, vf1, O[dt], 0, 0, 0);
        }
    }

    // reduce l across l16 lanes, write O/l to q slot
    #pragma unroll
    for (int r = 0; r < 4; r++) {
        float lv = l_lane[r];
        #pragma unroll
        for (int off = 1; off < 16; off <<= 1) lv += __shfl_xor(lv, off, 64);
        const float inv = 1.0f / lv;
        const int row = qt * 64 + wave * 16 + quad * 4 + r;
        u16* orow = qkvb + bb + (size_t)row * QKV_N + h * DHEAD;
        #pragma unroll
        for (int dt = 0; dt < 4; dt++)
            orow[dt * 16 + l16] = f2b(O[dt][r] * inv);
    }
}

// ---------------------------------------------------------------------------
extern "C" void kernel_launch(void* const* d_in, const int* in_sizes, int n_in,
                              void* d_out, int out_size, void* d_ws, size_t ws_size,
                              hipStream_t stream)
{
    const float* x      = (const float*)d_in[0];
    const float* cosb   = (const float*)d_in[1];
    const float* sinb   = (const float*)d_in[2];
    const float* qkv_w  = (const float*)d_in[3];
    const float* qkv_b  = (const float*)d_in[4];
    const float* proj_w = (const float*)d_in[5];
    const float* proj_b = (const float*)d_in[6];
    const float* qn_w   = (const float*)d_in[7];
    const float* kn_w   = (const float*)d_in[8];
    float* out = (float*)d_out;

    char* ws = (char*)d_ws;
    u16* qkvb = (u16*)(ws);                    // 4096 x 2304 bf16 = 18,874,368 B
    u16* xb   = (u16*)(ws + 18874368);         // 4096 x 768  bf16 =  6,291,456 B
    u16* wT   = (u16*)(ws + 25165824);         // 2304 x 768  bf16 =  3,538,944 B
    u16* pwT  = (u16*)(ws + 28704768);         //  768 x 768  bf16 =  1,179,648 B

    // 0. fused prep: x->bf16, both weight transposes
    prep_kernel<<<PREP_CONV + PREP_TQ + PREP_TP, 256, 0, stream>>>(
        x, xb, qkv_w, wT, proj_w, pwT);

    // 1. QKV projection + fused RMSNorm/RoPE -> bf16 qkv buffer
    gemm_qkv_mfma_kernel<<<dim3(QKV_N / 128, ROWS / 128), 256, 0, stream>>>(
        xb, CDIM, wT, qkv_b, cosb, sinb, qn_w, kn_w, qkvb, QKV_N, CDIM);

    // 2. Flash MFMA attention (out -> q slot of qkvb)
    attn_mfma_kernel<<<dim3(SEQ / 64, HEADS, BATCH), 256, 0, stream>>>(qkvb);

    // 3. Output projection (bf16 MFMA, fp32 out)
    gemm_proj_mfma_kernel<<<dim3(CDIM / 64, ROWS / 128), 256, 0, stream>>>(
        qkvb, QKV_N, pwT, proj_b, out, CDIM, CDIM);
}

// Round 8
// 195.902 us; speedup vs baseline: 32.1244x; 1.0205x over previous
//
#include <hip/hip_runtime.h>
#include <hip/hip_bf16.h>

// Problem constants
#define BATCH 2
#define SEQ   2048
#define CDIM  768
#define HEADS 12
#define DHEAD 64
#define QKV_N 2304   // 3*CDIM
#define ROWS  4096   // BATCH*SEQ

typedef unsigned short u16;
typedef unsigned int   u32;
typedef __attribute__((ext_vector_type(4))) float f32x4;
typedef __attribute__((ext_vector_type(8))) short bf16x8;
typedef __attribute__((ext_vector_type(4))) short bf16x4;

// fp32 -> bf16 (RNE) bit pattern
__device__ __forceinline__ u16 f2b(float f) {
    union { float f; unsigned u; } v; v.f = f;
    unsigned r = v.u + 0x7FFF + ((v.u >> 16) & 1u);
    return (u16)(r >> 16);
}
// bf16 bits -> fp32
__device__ __forceinline__ float b2f(u16 u) {
    union { unsigned i; float f; } x;
    x.i = ((unsigned)u) << 16;
    return x.f;
}
// fp32 -> bf16 round-to-nearest (no tie-to-even; 2 VALU ops)
__device__ __forceinline__ u16 f2b_rn(float f) {
    union { float f; unsigned u; } v; v.f = f;
    return (u16)((v.u + 0x8000u) >> 16);
}

// exp2: native v_exp_f32 when builtin available
#if __has_builtin(__builtin_amdgcn_exp2f)
#define EXP2(x) __builtin_amdgcn_exp2f(x)
#else
#define EXP2(x) __expf((x) * 0.69314718056f)
#endif

// async global->LDS 16B copy
__device__ __forceinline__ void load_lds16(const void* g, void* l) {
    __builtin_amdgcn_global_load_lds(
        (const __attribute__((address_space(1))) u32*)g,
        (__attribute__((address_space(3))) u32*)l, 16, 0, 0);
}

// ---------------------------------------------------------------------------
// Fused prep: x->bf16 (blocks [0,3072)), qkv_w transpose-convert
// (blocks [3072,4800)), proj_w transpose-convert (blocks [4800,5376)).
// ---------------------------------------------------------------------------
#define PREP_CONV 3072          // 4096*768/4 float4 / 256
#define PREP_TQ   1728          // (2304/32) x (768/32)
#define PREP_TP   576           // (768/32) x (768/32)

__device__ __forceinline__ void tconv_body(
    const float* __restrict__ in, u16* __restrict__ out, int R, int C,
    int bi, int bj)
{
    __shared__ float t[32][33];
    const int c = threadIdx.x & 31, r0 = threadIdx.x >> 5;
    #pragma unroll
    for (int i = 0; i < 4; i++) {
        const int r = r0 + i * 8;
        t[r][c] = in[(size_t)(bi * 32 + r) * C + bj * 32 + c];
    }
    __syncthreads();
    #pragma unroll
    for (int i = 0; i < 4; i++) {
        const int r = r0 + i * 8;
        out[(size_t)(bj * 32 + r) * R + bi * 32 + c] = f2b(t[c][r]);
    }
}

__global__ __launch_bounds__(256) void prep_kernel(
    const float* __restrict__ x, u16* __restrict__ xb,
    const float* __restrict__ qkv_w, u16* __restrict__ wT,
    const float* __restrict__ proj_w, u16* __restrict__ pwT)
{
    const int bid = blockIdx.x;
    if (bid < PREP_CONV) {
        const int i = bid * 256 + threadIdx.x;
        const float4 v = reinterpret_cast<const float4*>(x)[i];
        ushort4 o;
        o.x = f2b(v.x); o.y = f2b(v.y); o.z = f2b(v.z); o.w = f2b(v.w);
        reinterpret_cast<ushort4*>(xb)[i] = o;
    } else if (bid < PREP_CONV + PREP_TQ) {
        const int t = bid - PREP_CONV;
        tconv_body(qkv_w, wT, CDIM, QKV_N, t / 72, t % 72);
    } else {
        const int t = bid - PREP_CONV - PREP_TQ;
        tconv_body(proj_w, pwT, CDIM, CDIM, t / 24, t % 24);
    }
}

// ---------------------------------------------------------------------------
// bf16 MFMA GEMM 128x128 BK32 + FUSED RMSNorm + RoPE epilogue.
// q pre-scaled by Dh^-0.5 * log2(e) so attention can use exp2 directly.
// ---------------------------------------------------------------------------
__global__ __launch_bounds__(256) void gemm_qkv_mfma_kernel(
    const u16* __restrict__ A, int lda,
    const u16* __restrict__ BT,
    const float* __restrict__ bias,
    const float* __restrict__ cosb, const float* __restrict__ sinb,
    const float* __restrict__ qn, const float* __restrict__ kn,
    u16* __restrict__ C, int ldc, int K)
{
    __shared__ u16 sA[128 * 32];
    __shared__ u16 sB[128 * 32];
    const int tid = threadIdx.x;
    const int lane = tid & 63;
    const int wave = tid >> 6;
    const int wy = wave >> 1, wx = wave & 1;
    const int l16 = lane & 15, quad = lane >> 4;
    const int m0 = blockIdx.y * 128, n0 = blockIdx.x * 128;

    f32x4 acc[4][4] = {};

    for (int k0 = 0; k0 < K; k0 += 32) {
        __syncthreads();
        #pragma unroll
        for (int r = 0; r < 2; r++) {
            const int f = tid + r * 256;      // 16B granule id, 0..511
            const int row = f >> 2, g = f & 3;
            load_lds16(A  + (size_t)(m0 + row) * lda + k0 + g * 8, &sA[f * 8]);
            load_lds16(BT + (size_t)(n0 + row) * K   + k0 + g * 8, &sB[f * 8]);
        }
        __syncthreads();

        bf16x8 af[4], bfr[4];
        #pragma unroll
        for (int i = 0; i < 4; i++) {
            af[i]  = *reinterpret_cast<const bf16x8*>(
                &sA[(wy * 64 + i * 16 + l16) * 32 + quad * 8]);
            bfr[i] = *reinterpret_cast<const bf16x8*>(
                &sB[(wx * 64 + i * 16 + l16) * 32 + quad * 8]);
        }
        #pragma unroll
        for (int i = 0; i < 4; i++)
            #pragma unroll
            for (int j = 0; j < 4; j++)
                acc[i][j] = __builtin_amdgcn_mfma_f32_16x16x32_bf16(
                    af[i], bfr[j], acc[i][j], 0, 0, 0);
    }

    // ---- fused epilogue ----
    const int cb = (n0 + wx * 64) >> 6;   // 64-col block, 0..35
    const int s  = cb / 12;               // 0=q, 1=k, 2=v
    float bv[4];
    #pragma unroll
    for (int j = 0; j < 4; j++) bv[j] = bias[n0 + wx * 64 + j * 16 + l16];
    float wv[4];
    if (s < 2) {
        const float* wn = (s == 0) ? qn : kn;
        #pragma unroll
        for (int j = 0; j < 4; j++) wv[j] = wn[j * 16 + l16];
    }

    #pragma unroll
    for (int i = 0; i < 4; i++) {
        #pragma unroll
        for (int r = 0; r < 4; r++) {
            const int row = m0 + wy * 64 + i * 16 + quad * 4 + r;
            float v[4];
            #pragma unroll
            for (int j = 0; j < 4; j++) v[j] = acc[i][j][r] + bv[j];

            if (s < 2) {
                float sq = v[0]*v[0] + v[1]*v[1] + v[2]*v[2] + v[3]*v[3];
                #pragma unroll
                for (int off = 1; off < 16; off <<= 1)
                    sq += __shfl_xor(sq, off, 64);
                const float rms = rsqrtf(sq * (1.0f / 64.0f) + 1e-6f);
                const int n = row & (SEQ - 1);
                #pragma unroll
                for (int j = 0; j < 4; j++) {
                    const float nv = v[j] * rms * wv[j];
                    const float other = __shfl_xor(nv, 1, 64);
                    const int d = j * 16 + l16;
                    const float c  = cosb[n * 32 + (d >> 1)];
                    const float sn = sinb[n * 32 + (d >> 1)];
                    float res = ((l16 & 1) == 0) ? nv * c - other * sn
                                                 : other * sn + nv * c;
                    // fold Dh^-0.5 * log2(e) into q: scores land in exp2 domain
                    if (s == 0) res *= 0.18033688011112042f;
                    v[j] = res;
                }
            }
            #pragma unroll
            for (int j = 0; j < 4; j++) {
                const int col = n0 + wx * 64 + j * 16 + l16;
                C[(size_t)row * ldc + col] = f2b(v[j]);
            }
        }
    }
}

// ---------------------------------------------------------------------------
// bf16 MFMA GEMM 128x64 BK32, fp32 output + bias (final projection).
// ---------------------------------------------------------------------------
__global__ __launch_bounds__(256) void gemm_proj_mfma_kernel(
    const u16* __restrict__ A, int lda,
    const u16* __restrict__ BT,
    const float* __restrict__ bias,
    float* __restrict__ C, int ldc, int K)
{
    __shared__ u16 sA[128 * 32];
    __shared__ u16 sB[64 * 32];
    const int tid = threadIdx.x;
    const int lane = tid & 63;
    const int wave = tid >> 6;
    const int wy = wave >> 1, wx = wave & 1;
    const int l16 = lane & 15, quad = lane >> 4;
    const int m0 = blockIdx.y * 128, n0 = blockIdx.x * 64;

    f32x4 acc[4][2] = {};

    for (int k0 = 0; k0 < K; k0 += 32) {
        __syncthreads();
        #pragma unroll
        for (int r = 0; r < 2; r++) {
            const int f = tid + r * 256;
            const int row = f >> 2, g = f & 3;
            load_lds16(A + (size_t)(m0 + row) * lda + k0 + g * 8, &sA[f * 8]);
        }
        {
            const int row = tid >> 2, g = tid & 3;
            load_lds16(BT + (size_t)(n0 + row) * K + k0 + g * 8, &sB[tid * 8]);
        }
        __syncthreads();

        bf16x8 af[4], bfr[2];
        #pragma unroll
        for (int i = 0; i < 4; i++)
            af[i] = *reinterpret_cast<const bf16x8*>(
                &sA[(wy * 64 + i * 16 + l16) * 32 + quad * 8]);
        #pragma unroll
        for (int j = 0; j < 2; j++)
            bfr[j] = *reinterpret_cast<const bf16x8*>(
                &sB[(wx * 32 + j * 16 + l16) * 32 + quad * 8]);
        #pragma unroll
        for (int i = 0; i < 4; i++)
            #pragma unroll
            for (int j = 0; j < 2; j++)
                acc[i][j] = __builtin_amdgcn_mfma_f32_16x16x32_bf16(
                    af[i], bfr[j], acc[i][j], 0, 0, 0);
    }

    float bv[2];
    #pragma unroll
    for (int j = 0; j < 2; j++) bv[j] = bias[n0 + wx * 32 + j * 16 + l16];
    #pragma unroll
    for (int i = 0; i < 4; i++)
        #pragma unroll
        for (int r = 0; r < 4; r++) {
            const int row = m0 + wy * 64 + i * 16 + quad * 4 + r;
            #pragma unroll
            for (int j = 0; j < 2; j++) {
                const int col = n0 + wx * 32 + j * 16 + l16;
                C[(size_t)row * ldc + col] = acc[i][j][r] + bv[j];
            }
        }
}

// ---------------------------------------------------------------------------
// Flash MFMA attention, bf16-resident, fixed-max softmax (exp2 domain),
// double-buffered K/V LDS, conflict-mitigated layouts.
// ---------------------------------------------------------------------------
#define KP 80   // sK stride (u16)
#define PP 68   // sP stride (u16) = 34 words

__global__ __launch_bounds__(256) void attn_mfma_kernel(u16* __restrict__ qkvb)
{
    const int qt = blockIdx.x;   // q tile (64 rows)
    const int h  = blockIdx.y;
    const int b  = blockIdx.z;
    const int tid  = threadIdx.x;
    const int wave = tid >> 6;
    const int lane = tid & 63;
    const int l16  = lane & 15;
    const int quad = lane >> 4;

    const size_t bb = (size_t)b * SEQ * QKV_N;
    const u16* Kg = qkvb + bb + CDIM     + h * DHEAD;
    const u16* Vg = qkvb + bb + 2 * CDIM + h * DHEAD;
    const u16* Qg = qkvb + bb + (size_t)(qt * 64) * QKV_N + h * DHEAD;

    __shared__ u16 sK[2][64 * KP];
    __shared__ u32 sVt32[2][64 * 32];
    __shared__ u16 sP[64 * PP];

    // staging thread mapping
    const int kq = tid >> 3;      // K rows kq, kq+32
    const int g  = tid & 7;       // 16B granule (d = g*8..g*8+7)
    const int kp = tid >> 3;      // V key pair: rows 2kp, 2kp+1

    bf16x8 qf[2];
    {
        const u16* qrow = Qg + (size_t)(wave * 16 + l16) * QKV_N;
        qf[0] = *reinterpret_cast<const bf16x8*>(qrow + quad * 8);
        qf[1] = *reinterpret_cast<const bf16x8*>(qrow + 32 + quad * 8);
    }

    f32x4 O[4] = {};
    float l_lane[4] = {0.f, 0.f, 0.f, 0.f};

    bf16x8 kreg[2], vreg[2];
    kreg[0] = *reinterpret_cast<const bf16x8*>(Kg + (size_t)(kq)      * QKV_N + g * 8);
    kreg[1] = *reinterpret_cast<const bf16x8*>(Kg + (size_t)(kq + 32) * QKV_N + g * 8);
    vreg[0] = *reinterpret_cast<const bf16x8*>(Vg + (size_t)(2 * kp)     * QKV_N + g * 8);
    vreg[1] = *reinterpret_cast<const bf16x8*>(Vg + (size_t)(2 * kp + 1) * QKV_N + g * 8);

    for (int t = 0; t < SEQ / 64; t++) {
        const int cur = t & 1;
        // ---- write staged regs to LDS (buffer cur) ----
        *reinterpret_cast<bf16x8*>(&sK[cur][kq * KP + g * 8])        = kreg[0];
        *reinterpret_cast<bf16x8*>(&sK[cur][(kq + 32) * KP + g * 8]) = kreg[1];
        const int pwv = kp ^ (4 * g);
        #pragma unroll
        for (int e = 0; e < 8; e++) {
            const u32 pack = ((u32)(u16)vreg[0][e]) | (((u32)(u16)vreg[1][e]) << 16);
            sVt32[cur][(g * 8 + e) * 32 + pwv] = pack;
        }
        // ---- prefetch next tile into regs ----
        if (t + 1 < SEQ / 64) {
            const size_t base = (size_t)(t + 1) * 64;
            kreg[0] = *reinterpret_cast<const bf16x8*>(Kg + (base + kq)      * QKV_N + g * 8);
            kreg[1] = *reinterpret_cast<const bf16x8*>(Kg + (base + kq + 32) * QKV_N + g * 8);
            vreg[0] = *reinterpret_cast<const bf16x8*>(Vg + (base + 2 * kp)     * QKV_N + g * 8);
            vreg[1] = *reinterpret_cast<const bf16x8*>(Vg + (base + 2 * kp + 1) * QKV_N + g * 8);
        }
        __syncthreads();   // buffer cur fully written; prev buffer reads done

        // ---- S = Qs K^T  (scores already in exp2 domain) ----
        f32x4 s[4];
        #pragma unroll
        for (int kt = 0; kt < 4; kt++) {
            bf16x8 kf0 = *reinterpret_cast<const bf16x8*>(
                &sK[cur][(kt * 16 + l16) * KP + quad * 8]);
            bf16x8 kf1 = *reinterpret_cast<const bf16x8*>(
                &sK[cur][(kt * 16 + l16) * KP + 32 + quad * 8]);
            f32x4 a = {};
            a = __builtin_amdgcn_mfma_f32_16x16x32_bf16(qf[0], kf0, a, 0, 0, 0);
            a = __builtin_amdgcn_mfma_f32_16x16x32_bf16(qf[1], kf1, a, 0, 0, 0);
            s[kt] = a;
        }

        // ---- P = exp2(S) (|s|<=11.6, no max needed), accumulate l, P -> LDS
        #pragma unroll
        for (int kt = 0; kt < 4; kt++)
            #pragma unroll
            for (int r = 0; r < 4; r++) {
                const float p = EXP2(s[kt][r]);
                l_lane[r] += p;
                sP[(wave * 16 + quad * 4 + r) * PP + kt * 16 + l16] = f2b_rn(p);
            }
        // no barrier: sP rows wave-private (write->read ordered by lgkmcnt)

        // ---- O += P V ----
        union { bf16x8 v8; bf16x4 v4[2]; } p0u, p1u;
        {
            const int prow = (wave * 16 + l16) * PP;
            p0u.v4[0] = *reinterpret_cast<const bf16x4*>(&sP[prow + quad * 8]);
            p0u.v4[1] = *reinterpret_cast<const bf16x4*>(&sP[prow + quad * 8 + 4]);
            p1u.v4[0] = *reinterpret_cast<const bf16x4*>(&sP[prow + 32 + quad * 8]);
            p1u.v4[1] = *reinterpret_cast<const bf16x4*>(&sP[prow + 32 + quad * 8 + 4]);
        }
        #pragma unroll
        for (int dt = 0; dt < 4; dt++) {
            const int row = dt * 16 + l16;
            const int sw  = 4 * ((row >> 3) & 7);
            bf16x8 vf0 = *reinterpret_cast<const bf16x8*>(
                &sVt32[cur][row * 32 + ((quad * 4) ^ sw)]);
            bf16x8 vf1 = *reinterpret_cast<const bf16x8*>(
                &sVt32[cur][row * 32 + ((16 + quad * 4) ^ sw)]);
            O[dt] = __builtin_amdgcn_mfma_f32_16x16x32_bf16(p0u.v8, vf0, O[dt], 0, 0, 0);
            O[dt] = __builtin_amdgcn_mfma_f32_16x16x32_bf16(p1u.v8, vf1, O[dt], 0, 0, 0);
        }
    }

    // reduce l across l16 lanes, write O/l to q slot
    #pragma unroll
    for (int r = 0; r < 4; r++) {
        float lv = l_lane[r];
        #pragma unroll
        for (int off = 1; off < 16; off <<= 1) lv += __shfl_xor(lv, off, 64);
        const float inv = 1.0f / lv;
        const int row = qt * 64 + wave * 16 + quad * 4 + r;
        u16* orow = qkvb + bb + (size_t)row * QKV_N + h * DHEAD;
        #pragma unroll
        for (int dt = 0; dt < 4; dt++)
            orow[dt * 16 + l16] = f2b(O[dt][r] * inv);
    }
}

// ---------------------------------------------------------------------------
extern "C" void kernel_launch(void* const* d_in, const int* in_sizes, int n_in,
                              void* d_out, int out_size, void* d_ws, size_t ws_size,
                              hipStream_t stream)
{
    const float* x      = (const float*)d_in[0];
    const float* cosb   = (const float*)d_in[1];
    const float* sinb   = (const float*)d_in[2];
    const float* qkv_w  = (const float*)d_in[3];
    const float* qkv_b  = (const float*)d_in[4];
    const float* proj_w = (const float*)d_in[5];
    const float* proj_b = (const float*)d_in[6];
    const float* qn_w   = (const float*)d_in[7];
    const float* kn_w   = (const float*)d_in[8];
    float* out = (float*)d_out;

    char* ws = (char*)d_ws;
    u16* qkvb = (u16*)(ws);                    // 4096 x 2304 bf16 = 18,874,368 B
    u16* xb   = (u16*)(ws + 18874368);         // 4096 x 768  bf16 =  6,291,456 B
    u16* wT   = (u16*)(ws + 25165824);         // 2304 x 768  bf16 =  3,538,944 B
    u16* pwT  = (u16*)(ws + 28704768);         //  768 x 768  bf16 =  1,179,648 B

    // 0. fused prep: x->bf16, both weight transposes
    prep_kernel<<<PREP_CONV + PREP_TQ + PREP_TP, 256, 0, stream>>>(
        x, xb, qkv_w, wT, proj_w, pwT);

    // 1. QKV projection + fused RMSNorm/RoPE -> bf16 qkv buffer
    gemm_qkv_mfma_kernel<<<dim3(QKV_N / 128, ROWS / 128), 256, 0, stream>>>(
        xb, CDIM, wT, qkv_b, cosb, sinb, qn_w, kn_w, qkvb, QKV_N, CDIM);

    // 2. Flash MFMA attention (out -> q slot of qkvb)
    attn_mfma_kernel<<<dim3(SEQ / 64, HEADS, BATCH), 256, 0, stream>>>(qkvb);

    // 3. Output projection (bf16 MFMA, fp32 out)
    gemm_proj_mfma_kernel<<<dim3(CDIM / 64, ROWS / 128), 256, 0, stream>>>(
        qkvb, QKV_N, pwT, proj_b, out, CDIM, CDIM);
}

// Round 9
// 191.639 us; speedup vs baseline: 32.8390x; 1.0222x over previous
//
#include <hip/hip_runtime.h>
#include <hip/hip_bf16.h>

// Problem constants
#define BATCH 2
#define SEQ   2048
#define CDIM  768
#define HEADS 12
#define DHEAD 64
#define QKV_N 2304   // 3*CDIM
#define ROWS  4096   // BATCH*SEQ

typedef unsigned short u16;
typedef unsigned int   u32;
typedef __attribute__((ext_vector_type(4))) float f32x4;
typedef __attribute__((ext_vector_type(8))) short bf16x8;
typedef __attribute__((ext_vector_type(2))) unsigned int u32x2;

// fp32 -> bf16 (RNE) bit pattern
__device__ __forceinline__ u16 f2b(float f) {
    union { float f; unsigned u; } v; v.f = f;
    unsigned r = v.u + 0x7FFF + ((v.u >> 16) & 1u);
    return (u16)(r >> 16);
}
// bf16 bits -> fp32
__device__ __forceinline__ float b2f(u16 u) {
    union { unsigned i; float f; } x;
    x.i = ((unsigned)u) << 16;
    return x.f;
}
// fp32 -> bf16 round-to-nearest (no tie-to-even; 2 VALU ops)
__device__ __forceinline__ u32 b_rn(float f) {
    union { float f; unsigned u; } v; v.f = f;
    return (v.u + 0x8000u) >> 16;
}

// exp2: native v_exp_f32 when builtin available
#if __has_builtin(__builtin_amdgcn_exp2f)
#define EXP2(x) __builtin_amdgcn_exp2f(x)
#else
#define EXP2(x) __expf((x) * 0.69314718056f)
#endif

// async global->LDS 16B copy
__device__ __forceinline__ void load_lds16(const void* g, void* l) {
    __builtin_amdgcn_global_load_lds(
        (const __attribute__((address_space(1))) u32*)g,
        (__attribute__((address_space(3))) u32*)l, 16, 0, 0);
}

// ---------------------------------------------------------------------------
// Fused prep: x->bf16 (blocks [0,3072)), qkv_w transpose-convert
// (blocks [3072,4800)), proj_w transpose-convert (blocks [4800,5376)).
// ---------------------------------------------------------------------------
#define PREP_CONV 3072          // 4096*768/4 float4 / 256
#define PREP_TQ   1728          // (2304/32) x (768/32)
#define PREP_TP   576           // (768/32) x (768/32)

__device__ __forceinline__ void tconv_body(
    const float* __restrict__ in, u16* __restrict__ out, int R, int C,
    int bi, int bj)
{
    __shared__ float t[32][33];
    const int c = threadIdx.x & 31, r0 = threadIdx.x >> 5;
    #pragma unroll
    for (int i = 0; i < 4; i++) {
        const int r = r0 + i * 8;
        t[r][c] = in[(size_t)(bi * 32 + r) * C + bj * 32 + c];
    }
    __syncthreads();
    #pragma unroll
    for (int i = 0; i < 4; i++) {
        const int r = r0 + i * 8;
        out[(size_t)(bj * 32 + r) * R + bi * 32 + c] = f2b(t[c][r]);
    }
}

__global__ __launch_bounds__(256) void prep_kernel(
    const float* __restrict__ x, u16* __restrict__ xb,
    const float* __restrict__ qkv_w, u16* __restrict__ wT,
    const float* __restrict__ proj_w, u16* __restrict__ pwT)
{
    const int bid = blockIdx.x;
    if (bid < PREP_CONV) {
        const int i = bid * 256 + threadIdx.x;
        const float4 v = reinterpret_cast<const float4*>(x)[i];
        ushort4 o;
        o.x = f2b(v.x); o.y = f2b(v.y); o.z = f2b(v.z); o.w = f2b(v.w);
        reinterpret_cast<ushort4*>(xb)[i] = o;
    } else if (bid < PREP_CONV + PREP_TQ) {
        const int t = bid - PREP_CONV;
        tconv_body(qkv_w, wT, CDIM, QKV_N, t / 72, t % 72);
    } else {
        const int t = bid - PREP_CONV - PREP_TQ;
        tconv_body(proj_w, pwT, CDIM, CDIM, t / 24, t % 24);
    }
}

// ---------------------------------------------------------------------------
// bf16 MFMA GEMM 128x128 BK32 + FUSED RMSNorm + RoPE epilogue.
// q pre-scaled by Dh^-0.5 * log2(e) so attention can use exp2 directly.
// ---------------------------------------------------------------------------
__global__ __launch_bounds__(256) void gemm_qkv_mfma_kernel(
    const u16* __restrict__ A, int lda,
    const u16* __restrict__ BT,
    const float* __restrict__ bias,
    const float* __restrict__ cosb, const float* __restrict__ sinb,
    const float* __restrict__ qn, const float* __restrict__ kn,
    u16* __restrict__ C, int ldc, int K)
{
    __shared__ u16 sA[128 * 32];
    __shared__ u16 sB[128 * 32];
    const int tid = threadIdx.x;
    const int lane = tid & 63;
    const int wave = tid >> 6;
    const int wy = wave >> 1, wx = wave & 1;
    const int l16 = lane & 15, quad = lane >> 4;
    const int m0 = blockIdx.y * 128, n0 = blockIdx.x * 128;

    f32x4 acc[4][4] = {};

    for (int k0 = 0; k0 < K; k0 += 32) {
        __syncthreads();
        #pragma unroll
        for (int r = 0; r < 2; r++) {
            const int f = tid + r * 256;      // 16B granule id, 0..511
            const int row = f >> 2, g = f & 3;
            load_lds16(A  + (size_t)(m0 + row) * lda + k0 + g * 8, &sA[f * 8]);
            load_lds16(BT + (size_t)(n0 + row) * K   + k0 + g * 8, &sB[f * 8]);
        }
        __syncthreads();

        bf16x8 af[4], bfr[4];
        #pragma unroll
        for (int i = 0; i < 4; i++) {
            af[i]  = *reinterpret_cast<const bf16x8*>(
                &sA[(wy * 64 + i * 16 + l16) * 32 + quad * 8]);
            bfr[i] = *reinterpret_cast<const bf16x8*>(
                &sB[(wx * 64 + i * 16 + l16) * 32 + quad * 8]);
        }
        #pragma unroll
        for (int i = 0; i < 4; i++)
            #pragma unroll
            for (int j = 0; j < 4; j++)
                acc[i][j] = __builtin_amdgcn_mfma_f32_16x16x32_bf16(
                    af[i], bfr[j], acc[i][j], 0, 0, 0);
    }

    // ---- fused epilogue ----
    const int cb = (n0 + wx * 64) >> 6;   // 64-col block, 0..35
    const int s  = cb / 12;               // 0=q, 1=k, 2=v
    float bv[4];
    #pragma unroll
    for (int j = 0; j < 4; j++) bv[j] = bias[n0 + wx * 64 + j * 16 + l16];
    float wv[4];
    if (s < 2) {
        const float* wn = (s == 0) ? qn : kn;
        #pragma unroll
        for (int j = 0; j < 4; j++) wv[j] = wn[j * 16 + l16];
    }

    #pragma unroll
    for (int i = 0; i < 4; i++) {
        #pragma unroll
        for (int r = 0; r < 4; r++) {
            const int row = m0 + wy * 64 + i * 16 + quad * 4 + r;
            float v[4];
            #pragma unroll
            for (int j = 0; j < 4; j++) v[j] = acc[i][j][r] + bv[j];

            if (s < 2) {
                float sq = v[0]*v[0] + v[1]*v[1] + v[2]*v[2] + v[3]*v[3];
                #pragma unroll
                for (int off = 1; off < 16; off <<= 1)
                    sq += __shfl_xor(sq, off, 64);
                const float rms = rsqrtf(sq * (1.0f / 64.0f) + 1e-6f);
                const int n = row & (SEQ - 1);
                #pragma unroll
                for (int j = 0; j < 4; j++) {
                    const float nv = v[j] * rms * wv[j];
                    const float other = __shfl_xor(nv, 1, 64);
                    const int d = j * 16 + l16;
                    const float c  = cosb[n * 32 + (d >> 1)];
                    const float sn = sinb[n * 32 + (d >> 1)];
                    float res = ((l16 & 1) == 0) ? nv * c - other * sn
                                                 : other * sn + nv * c;
                    // fold Dh^-0.5 * log2(e) into q: scores land in exp2 domain
                    if (s == 0) res *= 0.18033688011112042f;
                    v[j] = res;
                }
            }
            #pragma unroll
            for (int j = 0; j < 4; j++) {
                const int col = n0 + wx * 64 + j * 16 + l16;
                C[(size_t)row * ldc + col] = f2b(v[j]);
            }
        }
    }
}

// ---------------------------------------------------------------------------
// bf16 MFMA GEMM 128x64 BK32, fp32 output + bias (final projection).
// ---------------------------------------------------------------------------
__global__ __launch_bounds__(256) void gemm_proj_mfma_kernel(
    const u16* __restrict__ A, int lda,
    const u16* __restrict__ BT,
    const float* __restrict__ bias,
    float* __restrict__ C, int ldc, int K)
{
    __shared__ u16 sA[128 * 32];
    __shared__ u16 sB[64 * 32];
    const int tid = threadIdx.x;
    const int lane = tid & 63;
    const int wave = tid >> 6;
    const int wy = wave >> 1, wx = wave & 1;
    const int l16 = lane & 15, quad = lane >> 4;
    const int m0 = blockIdx.y * 128, n0 = blockIdx.x * 64;

    f32x4 acc[4][2] = {};

    for (int k0 = 0; k0 < K; k0 += 32) {
        __syncthreads();
        #pragma unroll
        for (int r = 0; r < 2; r++) {
            const int f = tid + r * 256;
            const int row = f >> 2, g = f & 3;
            load_lds16(A + (size_t)(m0 + row) * lda + k0 + g * 8, &sA[f * 8]);
        }
        {
            const int row = tid >> 2, g = tid & 3;
            load_lds16(BT + (size_t)(n0 + row) * K + k0 + g * 8, &sB[tid * 8]);
        }
        __syncthreads();

        bf16x8 af[4], bfr[2];
        #pragma unroll
        for (int i = 0; i < 4; i++)
            af[i] = *reinterpret_cast<const bf16x8*>(
                &sA[(wy * 64 + i * 16 + l16) * 32 + quad * 8]);
        #pragma unroll
        for (int j = 0; j < 2; j++)
            bfr[j] = *reinterpret_cast<const bf16x8*>(
                &sB[(wx * 32 + j * 16 + l16) * 32 + quad * 8]);
        #pragma unroll
        for (int i = 0; i < 4; i++)
            #pragma unroll
            for (int j = 0; j < 2; j++)
                acc[i][j] = __builtin_amdgcn_mfma_f32_16x16x32_bf16(
                    af[i], bfr[j], acc[i][j], 0, 0, 0);
    }

    float bv[2];
    #pragma unroll
    for (int j = 0; j < 2; j++) bv[j] = bias[n0 + wx * 32 + j * 16 + l16];
    #pragma unroll
    for (int i = 0; i < 4; i++)
        #pragma unroll
        for (int r = 0; r < 4; r++) {
            const int row = m0 + wy * 64 + i * 16 + quad * 4 + r;
            #pragma unroll
            for (int j = 0; j < 2; j++) {
                const int col = n0 + wx * 32 + j * 16 + l16;
                C[(size_t)row * ldc + col] = acc[i][j][r] + bv[j];
            }
        }
}

// ---------------------------------------------------------------------------
// Flash MFMA attention, S^T-oriented:
//   S^T = mfma(kf, qf)  -> rows=keys, cols=q  (zero-cost operand swap)
//   P^T packed to sP[q][key] via 4x ds_write_b64 per wave-tile
//   O^T = mfma(vf, pf)  -> rows=d,   cols=q
//   l = one scalar per lane (col q), reduced over quads once at the end
// Fixed-max softmax in exp2 domain; double-buffered K/V; reg prefetch.
// ---------------------------------------------------------------------------
#define KP 80   // sK stride (u16)
#define PP 72   // sP stride (u16): 8B/16B-aligned rows, uniform bank spread

__global__ __launch_bounds__(256) void attn_mfma_kernel(u16* __restrict__ qkvb)
{
    const int qt = blockIdx.x;   // q tile (64 rows)
    const int h  = blockIdx.y;
    const int b  = blockIdx.z;
    const int tid  = threadIdx.x;
    const int wave = tid >> 6;
    const int lane = tid & 63;
    const int l16  = lane & 15;
    const int quad = lane >> 4;

    const size_t bb = (size_t)b * SEQ * QKV_N;
    const u16* Kg = qkvb + bb + CDIM     + h * DHEAD;
    const u16* Vg = qkvb + bb + 2 * CDIM + h * DHEAD;
    const u16* Qg = qkvb + bb + (size_t)(qt * 64) * QKV_N + h * DHEAD;

    __shared__ u16 sK[2][64 * KP];
    __shared__ u32 sVt32[2][64 * 32];
    __shared__ u16 sP[64 * PP];      // [q][key], q rows wave-private

    // staging thread mapping
    const int kq = tid >> 3;      // K rows kq, kq+32
    const int g  = tid & 7;       // 16B granule (d = g*8..g*8+7)
    const int kp = tid >> 3;      // V key pair: rows 2kp, 2kp+1

    bf16x8 qf[2];
    {
        const u16* qrow = Qg + (size_t)(wave * 16 + l16) * QKV_N;
        qf[0] = *reinterpret_cast<const bf16x8*>(qrow + quad * 8);
        qf[1] = *reinterpret_cast<const bf16x8*>(qrow + 32 + quad * 8);
    }

    f32x4 O[4] = {};        // O^T: rows d (quad*4+r within dt), cols q (l16)
    float l_acc = 0.f;      // per-lane: partial sum over keys for q = l16

    bf16x8 kreg[2], vreg[2];
    kreg[0] = *reinterpret_cast<const bf16x8*>(Kg + (size_t)(kq)      * QKV_N + g * 8);
    kreg[1] = *reinterpret_cast<const bf16x8*>(Kg + (size_t)(kq + 32) * QKV_N + g * 8);
    vreg[0] = *reinterpret_cast<const bf16x8*>(Vg + (size_t)(2 * kp)     * QKV_N + g * 8);
    vreg[1] = *reinterpret_cast<const bf16x8*>(Vg + (size_t)(2 * kp + 1) * QKV_N + g * 8);

    for (int t = 0; t < SEQ / 64; t++) {
        const int cur = t & 1;
        // ---- write staged regs to LDS (buffer cur) ----
        *reinterpret_cast<bf16x8*>(&sK[cur][kq * KP + g * 8])        = kreg[0];
        *reinterpret_cast<bf16x8*>(&sK[cur][(kq + 32) * KP + g * 8]) = kreg[1];
        const int pwv = kp ^ (4 * g);
        #pragma unroll
        for (int e = 0; e < 8; e++) {
            const u32 pack = ((u32)(u16)vreg[0][e]) | (((u32)(u16)vreg[1][e]) << 16);
            sVt32[cur][(g * 8 + e) * 32 + pwv] = pack;
        }
        // ---- prefetch next tile into regs ----
        if (t + 1 < SEQ / 64) {
            const size_t base = (size_t)(t + 1) * 64;
            kreg[0] = *reinterpret_cast<const bf16x8*>(Kg + (base + kq)      * QKV_N + g * 8);
            kreg[1] = *reinterpret_cast<const bf16x8*>(Kg + (base + kq + 32) * QKV_N + g * 8);
            vreg[0] = *reinterpret_cast<const bf16x8*>(Vg + (base + 2 * kp)     * QKV_N + g * 8);
            vreg[1] = *reinterpret_cast<const bf16x8*>(Vg + (base + 2 * kp + 1) * QKV_N + g * 8);
        }
        __syncthreads();   // buffer cur fully written; prev buffer reads done

        // ---- S^T = K Qs^T: rows = keys (kt*16 + quad*4 + r), cols = q (l16)
        f32x4 s[4];
        #pragma unroll
        for (int kt = 0; kt < 4; kt++) {
            bf16x8 kf0 = *reinterpret_cast<const bf16x8*>(
                &sK[cur][(kt * 16 + l16) * KP + quad * 8]);
            bf16x8 kf1 = *reinterpret_cast<const bf16x8*>(
                &sK[cur][(kt * 16 + l16) * KP + 32 + quad * 8]);
            f32x4 a = {};
            a = __builtin_amdgcn_mfma_f32_16x16x32_bf16(kf0, qf[0], a, 0, 0, 0);
            a = __builtin_amdgcn_mfma_f32_16x16x32_bf16(kf1, qf[1], a, 0, 0, 0);
            s[kt] = a;
        }

        // ---- P = exp2(S) (|s| bounded, no max), l += p, pack P^T -> LDS ----
        #pragma unroll
        for (int kt = 0; kt < 4; kt++) {
            float p0 = EXP2(s[kt][0]);
            float p1 = EXP2(s[kt][1]);
            float p2 = EXP2(s[kt][2]);
            float p3 = EXP2(s[kt][3]);
            l_acc += p0; l_acc += p1; l_acc += p2; l_acc += p3;
            u32x2 pk;
            pk.x = b_rn(p0) | (b_rn(p1) << 16);
            pk.y = b_rn(p2) | (b_rn(p3) << 16);
            // row q = wave*16+l16; keys kt*16 + quad*4 .. +3 (consecutive)
            *reinterpret_cast<u32x2*>(
                &sP[(wave * 16 + l16) * PP + kt * 16 + quad * 4]) = pk;
        }
        // no barrier: sP rows wave-private (write->read ordered by lgkmcnt)

        // ---- O^T += V^T P^T ----
        bf16x8 pf0 = *reinterpret_cast<const bf16x8*>(
            &sP[(wave * 16 + l16) * PP + quad * 8]);        // keys quad*8..+7
        bf16x8 pf1 = *reinterpret_cast<const bf16x8*>(
            &sP[(wave * 16 + l16) * PP + 32 + quad * 8]);   // keys 32+...
        #pragma unroll
        for (int dt = 0; dt < 4; dt++) {
            const int row = dt * 16 + l16;
            const int sw  = 4 * ((row >> 3) & 7);
            bf16x8 vf0 = *reinterpret_cast<const bf16x8*>(
                &sVt32[cur][row * 32 + ((quad * 4) ^ sw)]);
            bf16x8 vf1 = *reinterpret_cast<const bf16x8*>(
                &sVt32[cur][row * 32 + ((16 + quad * 4) ^ sw)]);
            O[dt] = __builtin_amdgcn_mfma_f32_16x16x32_bf16(vf0, pf0, O[dt], 0, 0, 0);
            O[dt] = __builtin_amdgcn_mfma_f32_16x16x32_bf16(vf1, pf1, O[dt], 0, 0, 0);
        }
    }

    // ---- epilogue: reduce l over quads, write O^T/l to q slot ----
    float lv = l_acc;
    lv += __shfl_xor(lv, 16, 64);
    lv += __shfl_xor(lv, 32, 64);
    const float inv = 1.0f / lv;
    const int qrow = qt * 64 + wave * 16 + l16;
    u16* orow = qkvb + bb + (size_t)qrow * QKV_N + h * DHEAD;
    #pragma unroll
    for (int dt = 0; dt < 4; dt++) {
        u32x2 pk;
        pk.x = b_rn(O[dt][0] * inv) | (b_rn(O[dt][1] * inv) << 16);
        pk.y = b_rn(O[dt][2] * inv) | (b_rn(O[dt][3] * inv) << 16);
        // d = dt*16 + quad*4 .. +3 (8B aligned)
        *reinterpret_cast<u32x2*>(&orow[dt * 16 + quad * 4]) = pk;
    }
}

// ---------------------------------------------------------------------------
extern "C" void kernel_launch(void* const* d_in, const int* in_sizes, int n_in,
                              void* d_out, int out_size, void* d_ws, size_t ws_size,
                              hipStream_t stream)
{
    const float* x      = (const float*)d_in[0];
    const float* cosb   = (const float*)d_in[1];
    const float* sinb   = (const float*)d_in[2];
    const float* qkv_w  = (const float*)d_in[3];
    const float* qkv_b  = (const float*)d_in[4];
    const float* proj_w = (const float*)d_in[5];
    const float* proj_b = (const float*)d_in[6];
    const float* qn_w   = (const float*)d_in[7];
    const float* kn_w   = (const float*)d_in[8];
    float* out = (float*)d_out;

    char* ws = (char*)d_ws;
    u16* qkvb = (u16*)(ws);                    // 4096 x 2304 bf16 = 18,874,368 B
    u16* xb   = (u16*)(ws + 18874368);         // 4096 x 768  bf16 =  6,291,456 B
    u16* wT   = (u16*)(ws + 25165824);         // 2304 x 768  bf16 =  3,538,944 B
    u16* pwT  = (u16*)(ws + 28704768);         //  768 x 768  bf16 =  1,179,648 B

    // 0. fused prep: x->bf16, both weight transposes
    prep_kernel<<<PREP_CONV + PREP_TQ + PREP_TP, 256, 0, stream>>>(
        x, xb, qkv_w, wT, proj_w, pwT);

    // 1. QKV projection + fused RMSNorm/RoPE -> bf16 qkv buffer
    gemm_qkv_mfma_kernel<<<dim3(QKV_N / 128, ROWS / 128), 256, 0, stream>>>(
        xb, CDIM, wT, qkv_b, cosb, sinb, qn_w, kn_w, qkvb, QKV_N, CDIM);

    // 2. Flash MFMA attention (out -> q slot of qkvb)
    attn_mfma_kernel<<<dim3(SEQ / 64, HEADS, BATCH), 256, 0, stream>>>(qkvb);

    // 3. Output projection (bf16 MFMA, fp32 out)
    gemm_proj_mfma_kernel<<<dim3(CDIM / 64, ROWS / 128), 256, 0, stream>>>(
        qkvb, QKV_N, pwT, proj_b, out, CDIM, CDIM);
}

// Round 11
// 186.727 us; speedup vs baseline: 33.7029x; 1.0263x over previous
//
#include <hip/hip_runtime.h>
#include <hip/hip_bf16.h>

// Problem constants
#define BATCH 2
#define SEQ   2048
#define CDIM  768
#define HEADS 12
#define DHEAD 64
#define QKV_N 2304   // 3*CDIM
#define ROWS  4096   // BATCH*SEQ

typedef unsigned short u16;
typedef unsigned int   u32;
typedef __attribute__((ext_vector_type(4))) float f32x4;
typedef __attribute__((ext_vector_type(8))) short bf16x8;
typedef __attribute__((ext_vector_type(2))) unsigned int u32x2;

// fp32 -> bf16 (RNE) bit pattern
__device__ __forceinline__ u16 f2b(float f) {
    union { float f; unsigned u; } v; v.f = f;
    unsigned r = v.u + 0x7FFF + ((v.u >> 16) & 1u);
    return (u16)(r >> 16);
}
// bf16 bits -> fp32
__device__ __forceinline__ float b2f(u16 u) {
    union { unsigned i; float f; } x;
    x.i = ((unsigned)u) << 16;
    return x.f;
}
// fp32 -> bf16 round-to-nearest (no tie-to-even; 2 VALU ops)
__device__ __forceinline__ u32 b_rn(float f) {
    union { float f; unsigned u; } v; v.f = f;
    return (v.u + 0x8000u) >> 16;
}

// exp2: native v_exp_f32 when builtin available
#if __has_builtin(__builtin_amdgcn_exp2f)
#define EXP2(x) __builtin_amdgcn_exp2f(x)
#else
#define EXP2(x) __expf((x) * 0.69314718056f)
#endif

// async global->LDS 16B copy
__device__ __forceinline__ void load_lds16(const void* g, void* l) {
    __builtin_amdgcn_global_load_lds(
        (const __attribute__((address_space(1))) u32*)g,
        (__attribute__((address_space(3))) u32*)l, 16, 0, 0);
}

// ---------------------------------------------------------------------------
// Fused prep: x->bf16 (blocks [0,3072)), qkv_w transpose-convert
// (blocks [3072,4800)), proj_w transpose-convert (blocks [4800,5376)).
// ---------------------------------------------------------------------------
#define PREP_CONV 3072          // 4096*768/4 float4 / 256
#define PREP_TQ   1728          // (2304/32) x (768/32)
#define PREP_TP   576           // (768/32) x (768/32)

__device__ __forceinline__ void tconv_body(
    const float* __restrict__ in, u16* __restrict__ out, int R, int C,
    int bi, int bj)
{
    __shared__ float t[32][33];
    const int c = threadIdx.x & 31, r0 = threadIdx.x >> 5;
    #pragma unroll
    for (int i = 0; i < 4; i++) {
        const int r = r0 + i * 8;
        t[r][c] = in[(size_t)(bi * 32 + r) * C + bj * 32 + c];
    }
    __syncthreads();
    #pragma unroll
    for (int i = 0; i < 4; i++) {
        const int r = r0 + i * 8;
        out[(size_t)(bj * 32 + r) * R + bi * 32 + c] = f2b(t[c][r]);
    }
}

__global__ __launch_bounds__(256) void prep_kernel(
    const float* __restrict__ x, u16* __restrict__ xb,
    const float* __restrict__ qkv_w, u16* __restrict__ wT,
    const float* __restrict__ proj_w, u16* __restrict__ pwT)
{
    const int bid = blockIdx.x;
    if (bid < PREP_CONV) {
        const int i = bid * 256 + threadIdx.x;
        const float4 v = reinterpret_cast<const float4*>(x)[i];
        ushort4 o;
        o.x = f2b(v.x); o.y = f2b(v.y); o.z = f2b(v.z); o.w = f2b(v.w);
        reinterpret_cast<ushort4*>(xb)[i] = o;
    } else if (bid < PREP_CONV + PREP_TQ) {
        const int t = bid - PREP_CONV;
        tconv_body(qkv_w, wT, CDIM, QKV_N, t / 72, t % 72);
    } else {
        const int t = bid - PREP_CONV - PREP_TQ;
        tconv_body(proj_w, pwT, CDIM, CDIM, t / 24, t % 24);
    }
}

// ---------------------------------------------------------------------------
// bf16 MFMA GEMM 128x128 BK32, DOUBLE-BUFFERED LDS (1 barrier/K-step),
// + FUSED RMSNorm + RoPE epilogue. q pre-scaled by Dh^-0.5 * log2(e).
// ---------------------------------------------------------------------------
__global__ __launch_bounds__(256) void gemm_qkv_mfma_kernel(
    const u16* __restrict__ A, int lda,
    const u16* __restrict__ BT,
    const float* __restrict__ bias,
    const float* __restrict__ cosb, const float* __restrict__ sinb,
    const float* __restrict__ qn, const float* __restrict__ kn,
    u16* __restrict__ C, int ldc, int K)
{
    __shared__ u16 sA[2][128 * 32];
    __shared__ u16 sB[2][128 * 32];
    const int tid = threadIdx.x;
    const int lane = tid & 63;
    const int wave = tid >> 6;
    const int wy = wave >> 1, wx = wave & 1;
    const int l16 = lane & 15, quad = lane >> 4;
    const int m0 = blockIdx.y * 128, n0 = blockIdx.x * 128;

    // staging indices (2 granules each of A and B per thread)
    const int srow0 = tid >> 2,         sg0 = tid & 3;
    const int srow1 = (tid + 256) >> 2, sg1 = tid & 3;   // f = tid+256

    f32x4 acc[4][4] = {};
    const int NK = K / 32;

    // prologue: stage k-step 0 into buffer 0
    load_lds16(A  + (size_t)(m0 + srow0) * lda + sg0 * 8, &sA[0][tid * 8]);
    load_lds16(BT + (size_t)(n0 + srow0) * K   + sg0 * 8, &sB[0][tid * 8]);
    load_lds16(A  + (size_t)(m0 + srow1) * lda + sg1 * 8, &sA[0][(tid + 256) * 8]);
    load_lds16(BT + (size_t)(n0 + srow1) * K   + sg1 * 8, &sB[0][(tid + 256) * 8]);

    for (int kt = 0; kt < NK; kt++) {
        const int cur = kt & 1;
        __syncthreads();   // DMA into buf[cur] complete; prior reads of buf[cur^1] done
        if (kt + 1 < NK) {
            const int nxt = cur ^ 1;
            const int k0 = (kt + 1) * 32;
            load_lds16(A  + (size_t)(m0 + srow0) * lda + k0 + sg0 * 8, &sA[nxt][tid * 8]);
            load_lds16(BT + (size_t)(n0 + srow0) * K   + k0 + sg0 * 8, &sB[nxt][tid * 8]);
            load_lds16(A  + (size_t)(m0 + srow1) * lda + k0 + sg1 * 8, &sA[nxt][(tid + 256) * 8]);
            load_lds16(BT + (size_t)(n0 + srow1) * K   + k0 + sg1 * 8, &sB[nxt][(tid + 256) * 8]);
        }

        bf16x8 af[4], bfr[4];
        #pragma unroll
        for (int i = 0; i < 4; i++) {
            af[i]  = *reinterpret_cast<const bf16x8*>(
                &sA[cur][(wy * 64 + i * 16 + l16) * 32 + quad * 8]);
            bfr[i] = *reinterpret_cast<const bf16x8*>(
                &sB[cur][(wx * 64 + i * 16 + l16) * 32 + quad * 8]);
        }
        #pragma unroll
        for (int i = 0; i < 4; i++)
            #pragma unroll
            for (int j = 0; j < 4; j++)
                acc[i][j] = __builtin_amdgcn_mfma_f32_16x16x32_bf16(
                    af[i], bfr[j], acc[i][j], 0, 0, 0);
    }

    // ---- fused epilogue ----
    const int cb = (n0 + wx * 64) >> 6;   // 64-col block, 0..35
    const int s  = cb / 12;               // 0=q, 1=k, 2=v
    float bv[4];
    #pragma unroll
    for (int j = 0; j < 4; j++) bv[j] = bias[n0 + wx * 64 + j * 16 + l16];
    float wv[4];
    if (s < 2) {
        const float* wn = (s == 0) ? qn : kn;
        #pragma unroll
        for (int j = 0; j < 4; j++) wv[j] = wn[j * 16 + l16];
    }

    #pragma unroll
    for (int i = 0; i < 4; i++) {
        #pragma unroll
        for (int r = 0; r < 4; r++) {
            const int row = m0 + wy * 64 + i * 16 + quad * 4 + r;
            float v[4];
            #pragma unroll
            for (int j = 0; j < 4; j++) v[j] = acc[i][j][r] + bv[j];

            if (s < 2) {
                float sq = v[0]*v[0] + v[1]*v[1] + v[2]*v[2] + v[3]*v[3];
                #pragma unroll
                for (int off = 1; off < 16; off <<= 1)
                    sq += __shfl_xor(sq, off, 64);
                const float rms = rsqrtf(sq * (1.0f / 64.0f) + 1e-6f);
                const int n = row & (SEQ - 1);
                #pragma unroll
                for (int j = 0; j < 4; j++) {
                    const float nv = v[j] * rms * wv[j];
                    const float other = __shfl_xor(nv, 1, 64);
                    const int d = j * 16 + l16;
                    const float c  = cosb[n * 32 + (d >> 1)];
                    const float sn = sinb[n * 32 + (d >> 1)];
                    float res = ((l16 & 1) == 0) ? nv * c - other * sn
                                                 : other * sn + nv * c;
                    // fold Dh^-0.5 * log2(e) into q: scores land in exp2 domain
                    if (s == 0) res *= 0.18033688011112042f;
                    v[j] = res;
                }
            }
            #pragma unroll
            for (int j = 0; j < 4; j++) {
                const int col = n0 + wx * 64 + j * 16 + l16;
                C[(size_t)row * ldc + col] = f2b(v[j]);
            }
        }
    }
}

// ---------------------------------------------------------------------------
// bf16 MFMA GEMM 64x64 BK32, double-buffered, fp32 output + bias.
// Grid = (N/64, M/64) = 768 blocks -> 3 blocks/CU.
// Wave w owns rows [w*16, w*16+16); ONE mfma_16x16x32 per col-tile per K-step
// (one MFMA consumes the full BK=32 via k = quad*8 + j).
// ---------------------------------------------------------------------------
__global__ __launch_bounds__(256) void gemm_proj_mfma_kernel(
    const u16* __restrict__ A, int lda,
    const u16* __restrict__ BT,
    const float* __restrict__ bias,
    float* __restrict__ C, int ldc, int K)
{
    __shared__ u16 sA[2][64 * 32];
    __shared__ u16 sB[2][64 * 32];
    const int tid = threadIdx.x;
    const int lane = tid & 63;
    const int wave = tid >> 6;
    const int l16 = lane & 15, quad = lane >> 4;
    const int m0 = blockIdx.y * 64, n0 = blockIdx.x * 64;

    const int srow = tid >> 2, sg = tid & 3;   // 256 granules per matrix

    f32x4 acc[4] = {};
    const int NK = K / 32;

    load_lds16(A  + (size_t)(m0 + srow) * lda + sg * 8, &sA[0][tid * 8]);
    load_lds16(BT + (size_t)(n0 + srow) * K   + sg * 8, &sB[0][tid * 8]);

    for (int kt = 0; kt < NK; kt++) {
        const int cur = kt & 1;
        __syncthreads();
        if (kt + 1 < NK) {
            const int nxt = cur ^ 1;
            const int k0 = (kt + 1) * 32;
            load_lds16(A  + (size_t)(m0 + srow) * lda + k0 + sg * 8, &sA[nxt][tid * 8]);
            load_lds16(BT + (size_t)(n0 + srow) * K   + k0 + sg * 8, &sB[nxt][tid * 8]);
        }

        const bf16x8 af = *reinterpret_cast<const bf16x8*>(
            &sA[cur][(wave * 16 + l16) * 32 + quad * 8]);
        bf16x8 bfr[4];
        #pragma unroll
        for (int j = 0; j < 4; j++)
            bfr[j] = *reinterpret_cast<const bf16x8*>(
                &sB[cur][(j * 16 + l16) * 32 + quad * 8]);
        #pragma unroll
        for (int j = 0; j < 4; j++)
            acc[j] = __builtin_amdgcn_mfma_f32_16x16x32_bf16(
                af, bfr[j], acc[j], 0, 0, 0);
    }

    float bv[4];
    #pragma unroll
    for (int j = 0; j < 4; j++) bv[j] = bias[n0 + j * 16 + l16];
    #pragma unroll
    for (int r = 0; r < 4; r++) {
        const int row = m0 + wave * 16 + quad * 4 + r;
        #pragma unroll
        for (int j = 0; j < 4; j++) {
            const int col = n0 + j * 16 + l16;
            C[(size_t)row * ldc + col] = acc[j][r] + bv[j];
        }
    }
}

// ---------------------------------------------------------------------------
// Flash MFMA attention, S^T-oriented (unchanged from round 9).
// ---------------------------------------------------------------------------
#define KP 80   // sK stride (u16)
#define PP 72   // sP stride (u16)

__global__ __launch_bounds__(256) void attn_mfma_kernel(u16* __restrict__ qkvb)
{
    const int qt = blockIdx.x;   // q tile (64 rows)
    const int h  = blockIdx.y;
    const int b  = blockIdx.z;
    const int tid  = threadIdx.x;
    const int wave = tid >> 6;
    const int lane = tid & 63;
    const int l16  = lane & 15;
    const int quad = lane >> 4;

    const size_t bb = (size_t)b * SEQ * QKV_N;
    const u16* Kg = qkvb + bb + CDIM     + h * DHEAD;
    const u16* Vg = qkvb + bb + 2 * CDIM + h * DHEAD;
    const u16* Qg = qkvb + bb + (size_t)(qt * 64) * QKV_N + h * DHEAD;

    __shared__ u16 sK[2][64 * KP];
    __shared__ u32 sVt32[2][64 * 32];
    __shared__ u16 sP[64 * PP];      // [q][key], q rows wave-private

    const int kq = tid >> 3;      // K rows kq, kq+32
    const int g  = tid & 7;       // 16B granule (d = g*8..g*8+7)
    const int kp = tid >> 3;      // V key pair: rows 2kp, 2kp+1

    bf16x8 qf[2];
    {
        const u16* qrow = Qg + (size_t)(wave * 16 + l16) * QKV_N;
        qf[0] = *reinterpret_cast<const bf16x8*>(qrow + quad * 8);
        qf[1] = *reinterpret_cast<const bf16x8*>(qrow + 32 + quad * 8);
    }

    f32x4 O[4] = {};        // O^T: rows d, cols q (l16)
    float l_acc = 0.f;

    bf16x8 kreg[2], vreg[2];
    kreg[0] = *reinterpret_cast<const bf16x8*>(Kg + (size_t)(kq)      * QKV_N + g * 8);
    kreg[1] = *reinterpret_cast<const bf16x8*>(Kg + (size_t)(kq + 32) * QKV_N + g * 8);
    vreg[0] = *reinterpret_cast<const bf16x8*>(Vg + (size_t)(2 * kp)     * QKV_N + g * 8);
    vreg[1] = *reinterpret_cast<const bf16x8*>(Vg + (size_t)(2 * kp + 1) * QKV_N + g * 8);

    for (int t = 0; t < SEQ / 64; t++) {
        const int cur = t & 1;
        *reinterpret_cast<bf16x8*>(&sK[cur][kq * KP + g * 8])        = kreg[0];
        *reinterpret_cast<bf16x8*>(&sK[cur][(kq + 32) * KP + g * 8]) = kreg[1];
        const int pwv = kp ^ (4 * g);
        #pragma unroll
        for (int e = 0; e < 8; e++) {
            const u32 pack = ((u32)(u16)vreg[0][e]) | (((u32)(u16)vreg[1][e]) << 16);
            sVt32[cur][(g * 8 + e) * 32 + pwv] = pack;
        }
        if (t + 1 < SEQ / 64) {
            const size_t base = (size_t)(t + 1) * 64;
            kreg[0] = *reinterpret_cast<const bf16x8*>(Kg + (base + kq)      * QKV_N + g * 8);
            kreg[1] = *reinterpret_cast<const bf16x8*>(Kg + (base + kq + 32) * QKV_N + g * 8);
            vreg[0] = *reinterpret_cast<const bf16x8*>(Vg + (base + 2 * kp)     * QKV_N + g * 8);
            vreg[1] = *reinterpret_cast<const bf16x8*>(Vg + (base + 2 * kp + 1) * QKV_N + g * 8);
        }
        __syncthreads();

        // S^T = K Qs^T
        f32x4 s[4];
        #pragma unroll
        for (int kt = 0; kt < 4; kt++) {
            bf16x8 kf0 = *reinterpret_cast<const bf16x8*>(
                &sK[cur][(kt * 16 + l16) * KP + quad * 8]);
            bf16x8 kf1 = *reinterpret_cast<const bf16x8*>(
                &sK[cur][(kt * 16 + l16) * KP + 32 + quad * 8]);
            f32x4 a = {};
            a = __builtin_amdgcn_mfma_f32_16x16x32_bf16(kf0, qf[0], a, 0, 0, 0);
            a = __builtin_amdgcn_mfma_f32_16x16x32_bf16(kf1, qf[1], a, 0, 0, 0);
            s[kt] = a;
        }

        // P = exp2(S), l += p, pack P^T -> LDS
        #pragma unroll
        for (int kt = 0; kt < 4; kt++) {
            float p0 = EXP2(s[kt][0]);
            float p1 = EXP2(s[kt][1]);
            float p2 = EXP2(s[kt][2]);
            float p3 = EXP2(s[kt][3]);
            l_acc += p0; l_acc += p1; l_acc += p2; l_acc += p3;
            u32x2 pk;
            pk.x = b_rn(p0) | (b_rn(p1) << 16);
            pk.y = b_rn(p2) | (b_rn(p3) << 16);
            *reinterpret_cast<u32x2*>(
                &sP[(wave * 16 + l16) * PP + kt * 16 + quad * 4]) = pk;
        }

        // O^T += V^T P^T
        bf16x8 pf0 = *reinterpret_cast<const bf16x8*>(
            &sP[(wave * 16 + l16) * PP + quad * 8]);
        bf16x8 pf1 = *reinterpret_cast<const bf16x8*>(
            &sP[(wave * 16 + l16) * PP + 32 + quad * 8]);
        #pragma unroll
        for (int dt = 0; dt < 4; dt++) {
            const int row = dt * 16 + l16;
            const int sw  = 4 * ((row >> 3) & 7);
            bf16x8 vf0 = *reinterpret_cast<const bf16x8*>(
                &sVt32[cur][row * 32 + ((quad * 4) ^ sw)]);
            bf16x8 vf1 = *reinterpret_cast<const bf16x8*>(
                &sVt32[cur][row * 32 + ((16 + quad * 4) ^ sw)]);
            O[dt] = __builtin_amdgcn_mfma_f32_16x16x32_bf16(vf0, pf0, O[dt], 0, 0, 0);
            O[dt] = __builtin_amdgcn_mfma_f32_16x16x32_bf16(vf1, pf1, O[dt], 0, 0, 0);
        }
    }

    // epilogue: reduce l over quads, write O^T/l to q slot
    float lv = l_acc;
    lv += __shfl_xor(lv, 16, 64);
    lv += __shfl_xor(lv, 32, 64);
    const float inv = 1.0f / lv;
    const int qrow = qt * 64 + wave * 16 + l16;
    u16* orow = qkvb + bb + (size_t)qrow * QKV_N + h * DHEAD;
    #pragma unroll
    for (int dt = 0; dt < 4; dt++) {
        u32x2 pk;
        pk.x = b_rn(O[dt][0] * inv) | (b_rn(O[dt][1] * inv) << 16);
        pk.y = b_rn(O[dt][2] * inv) | (b_rn(O[dt][3] * inv) << 16);
        *reinterpret_cast<u32x2*>(&orow[dt * 16 + quad * 4]) = pk;
    }
}

// ---------------------------------------------------------------------------
extern "C" void kernel_launch(void* const* d_in, const int* in_sizes, int n_in,
                              void* d_out, int out_size, void* d_ws, size_t ws_size,
                              hipStream_t stream)
{
    const float* x      = (const float*)d_in[0];
    const float* cosb   = (const float*)d_in[1];
    const float* sinb   = (const float*)d_in[2];
    const float* qkv_w  = (const float*)d_in[3];
    const float* qkv_b  = (const float*)d_in[4];
    const float* proj_w = (const float*)d_in[5];
    const float* proj_b = (const float*)d_in[6];
    const float* qn_w   = (const float*)d_in[7];
    const float* kn_w   = (const float*)d_in[8];
    float* out = (float*)d_out;

    char* ws = (char*)d_ws;
    u16* qkvb = (u16*)(ws);                    // 4096 x 2304 bf16 = 18,874,368 B
    u16* xb   = (u16*)(ws + 18874368);         // 4096 x 768  bf16 =  6,291,456 B
    u16* wT   = (u16*)(ws + 25165824);         // 2304 x 768  bf16 =  3,538,944 B
    u16* pwT  = (u16*)(ws + 28704768);         //  768 x 768  bf16 =  1,179,648 B

    // 0. fused prep: x->bf16, both weight transposes
    prep_kernel<<<PREP_CONV + PREP_TQ + PREP_TP, 256, 0, stream>>>(
        x, xb, qkv_w, wT, proj_w, pwT);

    // 1. QKV projection + fused RMSNorm/RoPE -> bf16 qkv buffer (dbuf)
    gemm_qkv_mfma_kernel<<<dim3(QKV_N / 128, ROWS / 128), 256, 0, stream>>>(
        xb, CDIM, wT, qkv_b, cosb, sinb, qn_w, kn_w, qkvb, QKV_N, CDIM);

    // 2. Flash MFMA attention (out -> q slot of qkvb)
    attn_mfma_kernel<<<dim3(SEQ / 64, HEADS, BATCH), 256, 0, stream>>>(qkvb);

    // 3. Output projection (bf16 MFMA 64x64 dbuf, fp32 out)
    gemm_proj_mfma_kernel<<<dim3(CDIM / 64, ROWS / 64), 256, 0, stream>>>(
        qkvb, QKV_N, pwT, proj_b, out, CDIM, CDIM);
}

// Round 12
// 184.255 us; speedup vs baseline: 34.1550x; 1.0134x over previous
//
#include <hip/hip_runtime.h>
#include <hip/hip_bf16.h>

// Problem constants
#define BATCH 2
#define SEQ   2048
#define CDIM  768
#define HEADS 12
#define DHEAD 64
#define QKV_N 2304   // 3*CDIM
#define ROWS  4096   // BATCH*SEQ

typedef unsigned short u16;
typedef unsigned int   u32;
typedef __attribute__((ext_vector_type(4))) float f32x4;
typedef __attribute__((ext_vector_type(8))) short bf16x8;
typedef __attribute__((ext_vector_type(2))) unsigned int u32x2;

// fp32 -> bf16 (RNE) bit pattern
__device__ __forceinline__ u16 f2b(float f) {
    union { float f; unsigned u; } v; v.f = f;
    unsigned r = v.u + 0x7FFF + ((v.u >> 16) & 1u);
    return (u16)(r >> 16);
}
// bf16 bits -> fp32
__device__ __forceinline__ float b2f(u16 u) {
    union { unsigned i; float f; } x;
    x.i = ((unsigned)u) << 16;
    return x.f;
}
// fp32 -> bf16 round-to-nearest (no tie-to-even; 2 VALU ops)
__device__ __forceinline__ u32 b_rn(float f) {
    union { float f; unsigned u; } v; v.f = f;
    return (v.u + 0x8000u) >> 16;
}

// exp2: native v_exp_f32 when builtin available
#if __has_builtin(__builtin_amdgcn_exp2f)
#define EXP2(x) __builtin_amdgcn_exp2f(x)
#else
#define EXP2(x) __expf((x) * 0.69314718056f)
#endif

// async global->LDS 16B copy
__device__ __forceinline__ void load_lds16(const void* g, void* l) {
    __builtin_amdgcn_global_load_lds(
        (const __attribute__((address_space(1))) u32*)g,
        (__attribute__((address_space(3))) u32*)l, 16, 0, 0);
}

// ---------------------------------------------------------------------------
// Fused prep: x->bf16 (blocks [0,3072)), qkv_w transpose-convert
// (blocks [3072,4800)), proj_w transpose-convert (blocks [4800,5376)).
// ---------------------------------------------------------------------------
#define PREP_CONV 3072          // 4096*768/4 float4 / 256
#define PREP_TQ   1728          // (2304/32) x (768/32)
#define PREP_TP   576           // (768/32) x (768/32)

__device__ __forceinline__ void tconv_body(
    const float* __restrict__ in, u16* __restrict__ out, int R, int C,
    int bi, int bj)
{
    __shared__ float t[32][33];
    const int c = threadIdx.x & 31, r0 = threadIdx.x >> 5;
    #pragma unroll
    for (int i = 0; i < 4; i++) {
        const int r = r0 + i * 8;
        t[r][c] = in[(size_t)(bi * 32 + r) * C + bj * 32 + c];
    }
    __syncthreads();
    #pragma unroll
    for (int i = 0; i < 4; i++) {
        const int r = r0 + i * 8;
        out[(size_t)(bj * 32 + r) * R + bi * 32 + c] = f2b(t[c][r]);
    }
}

__global__ __launch_bounds__(256) void prep_kernel(
    const float* __restrict__ x, u16* __restrict__ xb,
    const float* __restrict__ qkv_w, u16* __restrict__ wT,
    const float* __restrict__ proj_w, u16* __restrict__ pwT)
{
    const int bid = blockIdx.x;
    if (bid < PREP_CONV) {
        const int i = bid * 256 + threadIdx.x;
        const float4 v = reinterpret_cast<const float4*>(x)[i];
        ushort4 o;
        o.x = f2b(v.x); o.y = f2b(v.y); o.z = f2b(v.z); o.w = f2b(v.w);
        reinterpret_cast<ushort4*>(xb)[i] = o;
    } else if (bid < PREP_CONV + PREP_TQ) {
        const int t = bid - PREP_CONV;
        tconv_body(qkv_w, wT, CDIM, QKV_N, t / 72, t % 72);
    } else {
        const int t = bid - PREP_CONV - PREP_TQ;
        tconv_body(proj_w, pwT, CDIM, CDIM, t / 24, t % 24);
    }
}

// ---------------------------------------------------------------------------
// bf16 MFMA GEMM 128x128 BK32, DOUBLE-BUFFERED LDS (1 barrier/K-step),
// + FUSED RMSNorm + RoPE epilogue. q pre-scaled by Dh^-0.5 * log2(e).
// ---------------------------------------------------------------------------
__global__ __launch_bounds__(256) void gemm_qkv_mfma_kernel(
    const u16* __restrict__ A, int lda,
    const u16* __restrict__ BT,
    const float* __restrict__ bias,
    const float* __restrict__ cosb, const float* __restrict__ sinb,
    const float* __restrict__ qn, const float* __restrict__ kn,
    u16* __restrict__ C, int ldc, int K)
{
    __shared__ u16 sA[2][128 * 32];
    __shared__ u16 sB[2][128 * 32];
    const int tid = threadIdx.x;
    const int lane = tid & 63;
    const int wave = tid >> 6;
    const int wy = wave >> 1, wx = wave & 1;
    const int l16 = lane & 15, quad = lane >> 4;
    const int m0 = blockIdx.y * 128, n0 = blockIdx.x * 128;

    // staging indices (2 granules each of A and B per thread)
    const int srow0 = tid >> 2,         sg0 = tid & 3;
    const int srow1 = (tid + 256) >> 2, sg1 = tid & 3;   // f = tid+256

    f32x4 acc[4][4] = {};
    const int NK = K / 32;

    // prologue: stage k-step 0 into buffer 0
    load_lds16(A  + (size_t)(m0 + srow0) * lda + sg0 * 8, &sA[0][tid * 8]);
    load_lds16(BT + (size_t)(n0 + srow0) * K   + sg0 * 8, &sB[0][tid * 8]);
    load_lds16(A  + (size_t)(m0 + srow1) * lda + sg1 * 8, &sA[0][(tid + 256) * 8]);
    load_lds16(BT + (size_t)(n0 + srow1) * K   + sg1 * 8, &sB[0][(tid + 256) * 8]);

    for (int kt = 0; kt < NK; kt++) {
        const int cur = kt & 1;
        __syncthreads();   // DMA into buf[cur] complete; prior reads of buf[cur^1] done
        if (kt + 1 < NK) {
            const int nxt = cur ^ 1;
            const int k0 = (kt + 1) * 32;
            load_lds16(A  + (size_t)(m0 + srow0) * lda + k0 + sg0 * 8, &sA[nxt][tid * 8]);
            load_lds16(BT + (size_t)(n0 + srow0) * K   + k0 + sg0 * 8, &sB[nxt][tid * 8]);
            load_lds16(A  + (size_t)(m0 + srow1) * lda + k0 + sg1 * 8, &sA[nxt][(tid + 256) * 8]);
            load_lds16(BT + (size_t)(n0 + srow1) * K   + k0 + sg1 * 8, &sB[nxt][(tid + 256) * 8]);
        }

        bf16x8 af[4], bfr[4];
        #pragma unroll
        for (int i = 0; i < 4; i++) {
            af[i]  = *reinterpret_cast<const bf16x8*>(
                &sA[cur][(wy * 64 + i * 16 + l16) * 32 + quad * 8]);
            bfr[i] = *reinterpret_cast<const bf16x8*>(
                &sB[cur][(wx * 64 + i * 16 + l16) * 32 + quad * 8]);
        }
        #pragma unroll
        for (int i = 0; i < 4; i++)
            #pragma unroll
            for (int j = 0; j < 4; j++)
                acc[i][j] = __builtin_amdgcn_mfma_f32_16x16x32_bf16(
                    af[i], bfr[j], acc[i][j], 0, 0, 0);
    }

    // ---- fused epilogue ----
    const int cb = (n0 + wx * 64) >> 6;   // 64-col block, 0..35
    const int s  = cb / 12;               // 0=q, 1=k, 2=v
    float bv[4];
    #pragma unroll
    for (int j = 0; j < 4; j++) bv[j] = bias[n0 + wx * 64 + j * 16 + l16];
    float wv[4];
    if (s < 2) {
        const float* wn = (s == 0) ? qn : kn;
        #pragma unroll
        for (int j = 0; j < 4; j++) wv[j] = wn[j * 16 + l16];
    }

    #pragma unroll
    for (int i = 0; i < 4; i++) {
        #pragma unroll
        for (int r = 0; r < 4; r++) {
            const int row = m0 + wy * 64 + i * 16 + quad * 4 + r;
            float v[4];
            #pragma unroll
            for (int j = 0; j < 4; j++) v[j] = acc[i][j][r] + bv[j];

            if (s < 2) {
                float sq = v[0]*v[0] + v[1]*v[1] + v[2]*v[2] + v[3]*v[3];
                #pragma unroll
                for (int off = 1; off < 16; off <<= 1)
                    sq += __shfl_xor(sq, off, 64);
                const float rms = rsqrtf(sq * (1.0f / 64.0f) + 1e-6f);
                const int n = row & (SEQ - 1);
                #pragma unroll
                for (int j = 0; j < 4; j++) {
                    const float nv = v[j] * rms * wv[j];
                    const float other = __shfl_xor(nv, 1, 64);
                    const int d = j * 16 + l16;
                    const float c  = cosb[n * 32 + (d >> 1)];
                    const float sn = sinb[n * 32 + (d >> 1)];
                    float res = ((l16 & 1) == 0) ? nv * c - other * sn
                                                 : other * sn + nv * c;
                    // fold Dh^-0.5 * log2(e) into q: scores land in exp2 domain
                    if (s == 0) res *= 0.18033688011112042f;
                    v[j] = res;
                }
            }
            #pragma unroll
            for (int j = 0; j < 4; j++) {
                const int col = n0 + wx * 64 + j * 16 + l16;
                C[(size_t)row * ldc + col] = f2b(v[j]);
            }
        }
    }
}

// ---------------------------------------------------------------------------
// bf16 MFMA GEMM 64x64 BK32, double-buffered, fp32 output + bias.
// Grid = (N/64, M/64) = 768 blocks -> 3 blocks/CU.
// ---------------------------------------------------------------------------
__global__ __launch_bounds__(256) void gemm_proj_mfma_kernel(
    const u16* __restrict__ A, int lda,
    const u16* __restrict__ BT,
    const float* __restrict__ bias,
    float* __restrict__ C, int ldc, int K)
{
    __shared__ u16 sA[2][64 * 32];
    __shared__ u16 sB[2][64 * 32];
    const int tid = threadIdx.x;
    const int lane = tid & 63;
    const int wave = tid >> 6;
    const int l16 = lane & 15, quad = lane >> 4;
    const int m0 = blockIdx.y * 64, n0 = blockIdx.x * 64;

    const int srow = tid >> 2, sg = tid & 3;   // 256 granules per matrix

    f32x4 acc[4] = {};
    const int NK = K / 32;

    load_lds16(A  + (size_t)(m0 + srow) * lda + sg * 8, &sA[0][tid * 8]);
    load_lds16(BT + (size_t)(n0 + srow) * K   + sg * 8, &sB[0][tid * 8]);

    for (int kt = 0; kt < NK; kt++) {
        const int cur = kt & 1;
        __syncthreads();
        if (kt + 1 < NK) {
            const int nxt = cur ^ 1;
            const int k0 = (kt + 1) * 32;
            load_lds16(A  + (size_t)(m0 + srow) * lda + k0 + sg * 8, &sA[nxt][tid * 8]);
            load_lds16(BT + (size_t)(n0 + srow) * K   + k0 + sg * 8, &sB[nxt][tid * 8]);
        }

        const bf16x8 af = *reinterpret_cast<const bf16x8*>(
            &sA[cur][(wave * 16 + l16) * 32 + quad * 8]);
        bf16x8 bfr[4];
        #pragma unroll
        for (int j = 0; j < 4; j++)
            bfr[j] = *reinterpret_cast<const bf16x8*>(
                &sB[cur][(j * 16 + l16) * 32 + quad * 8]);
        #pragma unroll
        for (int j = 0; j < 4; j++)
            acc[j] = __builtin_amdgcn_mfma_f32_16x16x32_bf16(
                af, bfr[j], acc[j], 0, 0, 0);
    }

    float bv[4];
    #pragma unroll
    for (int j = 0; j < 4; j++) bv[j] = bias[n0 + j * 16 + l16];
    #pragma unroll
    for (int r = 0; r < 4; r++) {
        const int row = m0 + wave * 16 + quad * 4 + r;
        #pragma unroll
        for (int j = 0; j < 4; j++) {
            const int col = n0 + j * 16 + l16;
            C[(size_t)row * ldc + col] = acc[j][r] + bv[j];
        }
    }
}

// ---------------------------------------------------------------------------
// Flash MFMA attention, S^T-oriented, XOR-chunk-swizzled P buffer.
// sP: per q-row (l16, wave-private) 16 chunks of 8B (4 keys each);
// physical chunk = logical ^ l16. Writes: 4x ds_write_b64, each instruction
// covers all 16 positions exactly 4x -> 4 words/bank = conflict-free.
// Reads: 4x ds_read_b64, same uniformity.
// ---------------------------------------------------------------------------
#define KP 80   // sK stride (u16)

__global__ __launch_bounds__(256) void attn_mfma_kernel(u16* __restrict__ qkvb)
{
    const int qt = blockIdx.x;   // q tile (64 rows)
    const int h  = blockIdx.y;
    const int b  = blockIdx.z;
    const int tid  = threadIdx.x;
    const int wave = tid >> 6;
    const int lane = tid & 63;
    const int l16  = lane & 15;
    const int quad = lane >> 4;

    const size_t bb = (size_t)b * SEQ * QKV_N;
    const u16* Kg = qkvb + bb + CDIM     + h * DHEAD;
    const u16* Vg = qkvb + bb + 2 * CDIM + h * DHEAD;
    const u16* Qg = qkvb + bb + (size_t)(qt * 64) * QKV_N + h * DHEAD;

    __shared__ u16 sK[2][64 * KP];
    __shared__ u32 sVt32[2][64 * 32];
    __shared__ u32x2 sP2[64 * 16];   // [q][chunk^l16], 8B chunks, wave-private rows

    const int kq = tid >> 3;      // K rows kq, kq+32
    const int g  = tid & 7;       // 16B granule (d = g*8..g*8+7)
    const int kp = tid >> 3;      // V key pair: rows 2kp, 2kp+1

    bf16x8 qf[2];
    {
        const u16* qrow = Qg + (size_t)(wave * 16 + l16) * QKV_N;
        qf[0] = *reinterpret_cast<const bf16x8*>(qrow + quad * 8);
        qf[1] = *reinterpret_cast<const bf16x8*>(qrow + 32 + quad * 8);
    }

    f32x4 O[4] = {};        // O^T: rows d, cols q (l16)
    float l_acc = 0.f;

    bf16x8 kreg[2], vreg[2];
    kreg[0] = *reinterpret_cast<const bf16x8*>(Kg + (size_t)(kq)      * QKV_N + g * 8);
    kreg[1] = *reinterpret_cast<const bf16x8*>(Kg + (size_t)(kq + 32) * QKV_N + g * 8);
    vreg[0] = *reinterpret_cast<const bf16x8*>(Vg + (size_t)(2 * kp)     * QKV_N + g * 8);
    vreg[1] = *reinterpret_cast<const bf16x8*>(Vg + (size_t)(2 * kp + 1) * QKV_N + g * 8);

    const int prow = (wave * 16 + l16) * 16;

    for (int t = 0; t < SEQ / 64; t++) {
        const int cur = t & 1;
        *reinterpret_cast<bf16x8*>(&sK[cur][kq * KP + g * 8])        = kreg[0];
        *reinterpret_cast<bf16x8*>(&sK[cur][(kq + 32) * KP + g * 8]) = kreg[1];
        const int pwv = kp ^ (4 * g);
        #pragma unroll
        for (int e = 0; e < 8; e++) {
            const u32 pack = ((u32)(u16)vreg[0][e]) | (((u32)(u16)vreg[1][e]) << 16);
            sVt32[cur][(g * 8 + e) * 32 + pwv] = pack;
        }
        if (t + 1 < SEQ / 64) {
            const size_t base = (size_t)(t + 1) * 64;
            kreg[0] = *reinterpret_cast<const bf16x8*>(Kg + (base + kq)      * QKV_N + g * 8);
            kreg[1] = *reinterpret_cast<const bf16x8*>(Kg + (base + kq + 32) * QKV_N + g * 8);
            vreg[0] = *reinterpret_cast<const bf16x8*>(Vg + (base + 2 * kp)     * QKV_N + g * 8);
            vreg[1] = *reinterpret_cast<const bf16x8*>(Vg + (base + 2 * kp + 1) * QKV_N + g * 8);
        }
        __syncthreads();

        // S^T = K Qs^T: rows = keys (kt*16 + quad*4 + r), cols = q (l16)
        f32x4 s[4];
        #pragma unroll
        for (int kt = 0; kt < 4; kt++) {
            bf16x8 kf0 = *reinterpret_cast<const bf16x8*>(
                &sK[cur][(kt * 16 + l16) * KP + quad * 8]);
            bf16x8 kf1 = *reinterpret_cast<const bf16x8*>(
                &sK[cur][(kt * 16 + l16) * KP + 32 + quad * 8]);
            f32x4 a = {};
            a = __builtin_amdgcn_mfma_f32_16x16x32_bf16(kf0, qf[0], a, 0, 0, 0);
            a = __builtin_amdgcn_mfma_f32_16x16x32_bf16(kf1, qf[1], a, 0, 0, 0);
            s[kt] = a;
        }

        // P = exp2(S), l += p, pack P^T -> swizzled LDS chunks
        #pragma unroll
        for (int kt = 0; kt < 4; kt++) {
            float p0 = EXP2(s[kt][0]);
            float p1 = EXP2(s[kt][1]);
            float p2 = EXP2(s[kt][2]);
            float p3 = EXP2(s[kt][3]);
            l_acc += p0; l_acc += p1; l_acc += p2; l_acc += p3;
            u32x2 pk;
            pk.x = b_rn(p0) | (b_rn(p1) << 16);
            pk.y = b_rn(p2) | (b_rn(p3) << 16);
            sP2[prow + ((kt * 4 + quad) ^ l16)] = pk;   // keys kt*16+quad*4..+3
        }
        // no barrier: sP rows wave-private (write->read ordered by lgkmcnt)

        // O^T += V^T P^T  (reassemble pf from swizzled chunks)
        union { struct { u32x2 lo, hi; } s2; bf16x8 v; } pu0, pu1;
        pu0.s2.lo = sP2[prow + ((2 * quad)     ^ l16)];   // keys quad*8..+3
        pu0.s2.hi = sP2[prow + ((2 * quad + 1) ^ l16)];   // keys quad*8+4..+7
        pu1.s2.lo = sP2[prow + ((8 + 2 * quad) ^ l16)];   // keys 32+quad*8..+3
        pu1.s2.hi = sP2[prow + ((9 + 2 * quad) ^ l16)];   // keys 32+quad*8+4..+7
        #pragma unroll
        for (int dt = 0; dt < 4; dt++) {
            const int row = dt * 16 + l16;
            const int sw  = 4 * ((row >> 3) & 7);
            bf16x8 vf0 = *reinterpret_cast<const bf16x8*>(
                &sVt32[cur][row * 32 + ((quad * 4) ^ sw)]);
            bf16x8 vf1 = *reinterpret_cast<const bf16x8*>(
                &sVt32[cur][row * 32 + ((16 + quad * 4) ^ sw)]);
            O[dt] = __builtin_amdgcn_mfma_f32_16x16x32_bf16(vf0, pu0.v, O[dt], 0, 0, 0);
            O[dt] = __builtin_amdgcn_mfma_f32_16x16x32_bf16(vf1, pu1.v, O[dt], 0, 0, 0);
        }
    }

    // epilogue: reduce l over quads, write O^T/l to q slot
    float lv = l_acc;
    lv += __shfl_xor(lv, 16, 64);
    lv += __shfl_xor(lv, 32, 64);
    const float inv = 1.0f / lv;
    const int qrow = qt * 64 + wave * 16 + l16;
    u16* orow = qkvb + bb + (size_t)qrow * QKV_N + h * DHEAD;
    #pragma unroll
    for (int dt = 0; dt < 4; dt++) {
        u32x2 pk;
        pk.x = b_rn(O[dt][0] * inv) | (b_rn(O[dt][1] * inv) << 16);
        pk.y = b_rn(O[dt][2] * inv) | (b_rn(O[dt][3] * inv) << 16);
        *reinterpret_cast<u32x2*>(&orow[dt * 16 + quad * 4]) = pk;
    }
}

// ---------------------------------------------------------------------------
extern "C" void kernel_launch(void* const* d_in, const int* in_sizes, int n_in,
                              void* d_out, int out_size, void* d_ws, size_t ws_size,
                              hipStream_t stream)
{
    const float* x      = (const float*)d_in[0];
    const float* cosb   = (const float*)d_in[1];
    const float* sinb   = (const float*)d_in[2];
    const float* qkv_w  = (const float*)d_in[3];
    const float* qkv_b  = (const float*)d_in[4];
    const float* proj_w = (const float*)d_in[5];
    const float* proj_b = (const float*)d_in[6];
    const float* qn_w   = (const float*)d_in[7];
    const float* kn_w   = (const float*)d_in[8];
    float* out = (float*)d_out;

    char* ws = (char*)d_ws;
    u16* qkvb = (u16*)(ws);                    // 4096 x 2304 bf16 = 18,874,368 B
    u16* xb   = (u16*)(ws + 18874368);         // 4096 x 768  bf16 =  6,291,456 B
    u16* wT   = (u16*)(ws + 25165824);         // 2304 x 768  bf16 =  3,538,944 B
    u16* pwT  = (u16*)(ws + 28704768);         //  768 x 768  bf16 =  1,179,648 B

    // 0. fused prep: x->bf16, both weight transposes
    prep_kernel<<<PREP_CONV + PREP_TQ + PREP_TP, 256, 0, stream>>>(
        x, xb, qkv_w, wT, proj_w, pwT);

    // 1. QKV projection + fused RMSNorm/RoPE -> bf16 qkv buffer (dbuf)
    gemm_qkv_mfma_kernel<<<dim3(QKV_N / 128, ROWS / 128), 256, 0, stream>>>(
        xb, CDIM, wT, qkv_b, cosb, sinb, qn_w, kn_w, qkvb, QKV_N, CDIM);

    // 2. Flash MFMA attention (out -> q slot of qkvb)
    attn_mfma_kernel<<<dim3(SEQ / 64, HEADS, BATCH), 256, 0, stream>>>(qkvb);

    // 3. Output projection (bf16 MFMA 64x64 dbuf, fp32 out)
    gemm_proj_mfma_kernel<<<dim3(CDIM / 64, ROWS / 64), 256, 0, stream>>>(
        qkvb, QKV_N, pwT, proj_b, out, CDIM, CDIM);
}